// Round 6
// baseline (160.276 us; speedup 1.0000x reference)
//
#include <hip/hip_runtime.h>
#include <math.h>

#define DEVI __device__ __forceinline__

constexpr int Bb = 4, Nn = 16384, Kk = 4;
constexpr int NCH = 64;                  // fg chunks per b
constexpr int CH = 256;                  // n per fg chunk
constexpr int FG_BLK = Bb * NCH;         // 256
constexpr int NBG = 64;                  // bg chunks per b
constexpr int BG_BLK = Bb * NBG;         // 256
constexpr int FG_PS = 72;                // m,s,px,py,swx,swy,swm,pad,upd[64]
constexpr int BG_PS = 130;               // m,s,upd[64],sumv[64]

typedef __attribute__((ext_vector_type(8))) short bf16x8;
typedef __attribute__((ext_vector_type(8))) unsigned short u16x8;
typedef __attribute__((ext_vector_type(4))) unsigned short u16x4;
typedef __attribute__((ext_vector_type(4))) float f32x4;

DEVI float bf2f(unsigned short u){ unsigned int x = ((unsigned int)u) << 16; return __builtin_bit_cast(float, x); }
DEVI unsigned short f2bf(float f){
  unsigned int u = __builtin_bit_cast(unsigned int, f);
  u += 0x7fffu + ((u >> 16) & 1u);
  return (unsigned short)(u >> 16);
}
DEVI float rsum_16_32(float v){ v += __shfl_xor(v,16); v += __shfl_xor(v,32); return v; }
DEVI float rmax_16_32(float v){ v = fmaxf(v,__shfl_xor(v,16)); v = fmaxf(v,__shfl_xor(v,32)); return v; }
DEVI float rsum_1_8(float v){ v += __shfl_xor(v,1); v += __shfl_xor(v,2); v += __shfl_xor(v,4); v += __shfl_xor(v,8); return v; }
DEVI float rmax_1_8(float v){ v = fmaxf(v,__shfl_xor(v,1)); v = fmaxf(v,__shfl_xor(v,2)); v = fmaxf(v,__shfl_xor(v,4)); v = fmaxf(v,__shfl_xor(v,8)); return v; }
DEVI float rsum_all(float v){ return rsum_16_32(rsum_1_8(v)); }
DEVI float rmax_all(float v){ return rmax_16_32(rmax_1_8(v)); }
DEVI float sel4(float a0, float a1, float a2, float a3, int r){
  float v = a0; v = (r == 1) ? a1 : v; v = (r == 2) ? a2 : v; v = (r == 3) ? a3 : v; return v;
}
DEVI float sigm(float x){ return 1.f / (1.f + __expf(-x)); }

constexpr float GSTEP = 2.0f / 127.0f;
DEVI float gxf(int n){ return (float)(n & 127) * GSTEP - 1.0f; }
DEVI float gyf(int n){ return (float)((n >> 7) & 127) * GSTEP - 1.0f; }

#define NEGINF (-__builtin_inff())

// ---------------------------------------------------------------- k_prep
// blocks 0..1023: main projection (1 tile of 16 rows per wave)
// blocks 1024..1027: fg_pos from mask; 1028: cbuf; 1029..1048: slot init
__global__ __launch_bounds__(256) void k_prep(
    const float* __restrict__ feat,
    const float* __restrict__ norm_g, const float* __restrict__ norm_b,
    const float* __restrict__ gw, const float* __restrict__ gb,
    const float* __restrict__ k_fg_w, const float* __restrict__ v_fg_w,
    const float* __restrict__ k_bg_w, const float* __restrict__ v_bg_w,
    const float* __restrict__ mlp_bg_ln_g, const float* __restrict__ mlp_bg_ln_b,
    const float* __restrict__ mlp_bg_w, const float* __restrict__ mlp_bg_b,
    const float* __restrict__ mlp_fg_ln_g, const float* __restrict__ mlp_fg_ln_b,
    const float* __restrict__ mlp_fg_w, const float* __restrict__ mlp_fg_b,
    const float* __restrict__ mask,
    unsigned short* __restrict__ A_k, unsigned short* __restrict__ A_vT,
    float* __restrict__ statsKV,
    unsigned short* __restrict__ kbg, unsigned short* __restrict__ vbg,
    const float* __restrict__ noise_fg, const float* __restrict__ noise_bg,
    const float* __restrict__ mu, const float* __restrict__ ls,
    const float* __restrict__ mub, const float* __restrict__ lsb,
    const float* __restrict__ q_ln_g, const float* __restrict__ q_ln_b, const float* __restrict__ q_w,
    const float* __restrict__ qbg_ln_g, const float* __restrict__ qbg_ln_b, const float* __restrict__ qbg_w,
    float* slot_fg0, float* slot_bg0, float* q_fg, float* q_bg,
    float* __restrict__ fg_pos, float* __restrict__ cbuf)
{
  int tid = threadIdx.x, wave = tid >> 6, l = tid & 63;
  if ((int)blockIdx.x >= 1024) {
    int ib = blockIdx.x - 1024;
    if (ib < 4) {
      // fg_pos from mask (256 threads, 16 float4 each)
      int k = ib;
      const float4* mp = (const float4*)(mask + (size_t)k * Nn);
      float sm = 0, sx = 0, sy = 0;
      #pragma unroll
      for (int i = 0; i < 16; ++i) {
        int idx = tid + i * 256;
        float4 v = mp[idx];
        int n = idx * 4;
        float gy = gyf(n);
        float rowsum = v.x + v.y + v.z + v.w;
        sm += rowsum;
        sx += v.x * gxf(n) + v.y * gxf(n + 1) + v.z * gxf(n + 2) + v.w * gxf(n + 3);
        sy += rowsum * gy;
      }
      sm = rsum_all(sm); sx = rsum_all(sx); sy = rsum_all(sy);
      __shared__ float red[3][4];
      if (l == 0) { red[0][wave] = sm; red[1][wave] = sx; red[2][wave] = sy; }
      __syncthreads();
      if (tid == 0) {
        float S = red[0][0]+red[0][1]+red[0][2]+red[0][3];
        float X = red[1][0]+red[1][1]+red[1][2]+red[1][3];
        float Y = red[2][0]+red[2][1]+red[2][2]+red[2][3];
        float inv = 1.f / (S + 1e-5f);
        float px = X * inv, py = Y * inv;
        for (int b = 0; b < 4; ++b) { fg_pos[(b*4+k)*2+0] = px; fg_pos[(b*4+k)*2+1] = py; }
      }
    } else if (ib == 4) {
      // cbuf constants
      if (tid < 64) {
        int t = tid;
        float gx_t = gw[t*4+0] - gw[t*4+2];
        float gy_t = gw[t*4+1] - gw[t*4+3];
        float aGx = 0, aGy = 0, agW = 0, aC0 = 0;
        for (int c = 0; c < 64; ++c) {
          float wv = mlp_fg_w[t*64 + c];
          float gc = mlp_fg_ln_g[c];
          float gxc = gw[c*4+0] - gw[c*4+2];
          float gyc = gw[c*4+1] - gw[c*4+3];
          aGx += gxc * gc * wv;
          aGy += gyc * gc * wv;
          agW += gc * wv;
          aC0 += mlp_fg_ln_b[c] * wv;
        }
        cbuf[t] = aGx; cbuf[64+t] = aGy; cbuf[128+t] = agW; cbuf[192+t] = aC0 + mlp_fg_b[t];
        float mgx = rsum_all(gx_t) * (1.f/64.f);
        float mgy = rsum_all(gy_t) * (1.f/64.f);
        float egx2 = rsum_all(gx_t*gx_t) * (1.f/64.f);
        float egy2 = rsum_all(gy_t*gy_t) * (1.f/64.f);
        float egxy = rsum_all(gx_t*gy_t) * (1.f/64.f);
        if (t == 0) { cbuf[256]=mgx; cbuf[257]=mgy; cbuf[258]=egx2; cbuf[259]=egy2; cbuf[260]=egxy; }
      }
    } else {
      // slot init (20 blocks), wave0 active
      __shared__ float lds[64];
      int jb = ib - 5;
      if (tid < 64) {
        float lnv;
        if (jb < 16) {
          float s = mu[tid] + expf(ls[tid]) * noise_fg[jb * 64 + tid];
          slot_fg0[jb * 64 + tid] = s;
          float mean = rsum_all(s) * (1.f / 64.f);
          float d = s - mean;
          float var = rsum_all(d * d) * (1.f / 64.f);
          lnv = d * rsqrtf(var + 1e-5f) * q_ln_g[tid] + q_ln_b[tid];
        } else {
          int b = jb - 16;
          float s = mub[tid] + expf(lsb[tid]) * noise_bg[b * 64 + tid];
          slot_bg0[b * 64 + tid] = s;
          float mean = rsum_all(s) * (1.f / 64.f);
          float d = s - mean;
          float var = rsum_all(d * d) * (1.f / 64.f);
          lnv = d * rsqrtf(var + 1e-5f) * qbg_ln_g[tid] + qbg_ln_b[tid];
        }
        lds[tid] = lnv;
      }
      __syncthreads();
      if (tid < 64) {
        if (jb < 16) {
          float acc = 0.f;
          #pragma unroll 8
          for (int c = 0; c < 64; ++c) acc += q_w[tid * 64 + c] * lds[c];
          q_fg[jb * 64 + tid] = acc;
        } else {
          int b = jb - 16;
          float acc = 0.f;
          #pragma unroll 8
          for (int c = 0; c < 64; ++c) acc += qbg_w[tid * 64 + c] * lds[c];
          q_bg[b * 64 + tid] = acc;
        }
      }
    }
    return;
  }
  __shared__ bf16x8 wfrag[6 * 8 * 64];
  __shared__ __align__(16) unsigned short tbuf[4][16][88];
  __shared__ float s_gwx[64], s_gwy[64], s_gb[64], s_mlg[64], s_mlb[64], s_mbb[64], s_gf[64];
  const float* wsrc[6] = { k_fg_w, v_fg_w, k_bg_w, v_bg_w, mlp_bg_w, mlp_fg_w };
  for (int mi = wave; mi < 6; mi += 4) {
    const float* ws = wsrc[mi];
    #pragma unroll
    for (int f = 0; f < 8; ++f) {
      int ct = f >> 1, kh = f & 1;
      int row = ct * 16 + (l & 15);
      int c0 = ((l >> 4) << 3) + kh * 32;
      bf16x8 v;
      #pragma unroll
      for (int j = 0; j < 8; ++j) v[j] = (short)f2bf(ws[row * 64 + c0 + j]);
      wfrag[(mi * 8 + f) * 64 + l] = v;
    }
  }
  if (tid < 64) {
    s_gwx[tid] = gw[tid*4+0] - gw[tid*4+2];
    s_gwy[tid] = gw[tid*4+1] - gw[tid*4+3];
    s_gb[tid]  = gb[tid];
    s_mlg[tid] = mlp_bg_ln_g[tid];
    s_mlb[tid] = mlp_bg_ln_b[tid];
    s_mbb[tid] = mlp_bg_b[tid];
    s_gf[tid]  = mlp_fg_ln_g[tid];
  }
  __syncthreads();

  int cb = (l >> 4) << 3;
  float ngr[16], nbr[16];
  #pragma unroll
  for (int j = 0; j < 16; ++j) {
    int col = (j < 8) ? (cb + j) : (32 + cb + j - 8);
    ngr[j] = norm_g[col]; nbr[j] = norm_b[col];
  }
  float gwxD[4], gwyD[4], gbD[4], mlgD[4], mlbD[4], mbbD[4], gfD[4];
  #pragma unroll
  for (int ct = 0; ct < 4; ++ct) {
    int col = ct * 16 + (l & 15);
    gwxD[ct] = s_gwx[col]; gwyD[ct] = s_gwy[col]; gbD[ct] = s_gb[col];
    mlgD[ct] = s_mlg[col]; mlbD[ct] = s_mlb[col]; mbbD[ct] = s_mbb[col];
    gfD[ct] = s_gf[col];
  }

  int tile = blockIdx.x * 4 + wave;
  {
    int rowg = tile * 16 + (l & 15);
    const float* fp = feat + (size_t)rowg * 64;
    float x[16];
    #pragma unroll
    for (int j = 0; j < 8; ++j) x[j] = fp[cb + j];
    #pragma unroll
    for (int j = 0; j < 8; ++j) x[8 + j] = fp[32 + cb + j];
    float sm = 0;
    #pragma unroll
    for (int j = 0; j < 16; ++j) sm += x[j];
    float mean = rsum_16_32(sm) * (1.f / 64.f);
    float vv = 0;
    #pragma unroll
    for (int j = 0; j < 16; ++j) { float d = x[j] - mean; vv += d * d; }
    float rstd = rsqrtf(rsum_16_32(vv) * (1.f / 64.f) + 1e-5f);
    bf16x8 a0, a1;
    #pragma unroll
    for (int j = 0; j < 8; ++j) a0[j] = (short)f2bf((x[j] - mean) * rstd * ngr[j] + nbr[j]);
    #pragma unroll
    for (int j = 0; j < 8; ++j) a1[j] = (short)f2bf((x[8 + j] - mean) * rstd * ngr[8 + j] + nbr[8 + j]);

    for (int mi = 0; mi < 4; ++mi) {
      f32x4 acc[4];
      #pragma unroll
      for (int ct = 0; ct < 4; ++ct) acc[ct] = (f32x4){0.f, 0.f, 0.f, 0.f};
      #pragma unroll
      for (int ct = 0; ct < 4; ++ct) {
        acc[ct] = __builtin_amdgcn_mfma_f32_16x16x32_bf16(a0, wfrag[(mi * 8 + ct * 2 + 0) * 64 + l], acc[ct], 0, 0, 0);
        acc[ct] = __builtin_amdgcn_mfma_f32_16x16x32_bf16(a1, wfrag[(mi * 8 + ct * 2 + 1) * 64 + l], acc[ct], 0, 0, 0);
      }
      if (mi < 2) {
        #pragma unroll
        for (int ct = 0; ct < 4; ++ct)
          #pragma unroll
          for (int r = 0; r < 4; ++r)
            acc[ct][r] += gbD[ct];
        float s1[4], s2[4], sx[4], sy[4];
        #pragma unroll
        for (int r = 0; r < 4; ++r) {
          float a0v = acc[0][r], a1v = acc[1][r], a2v = acc[2][r], a3v = acc[3][r];
          s1[r] = rsum_1_8(a0v + a1v + a2v + a3v);
          s2[r] = rsum_1_8(a0v*a0v + a1v*a1v + a2v*a2v + a3v*a3v);
          sx[r] = rsum_1_8(a0v*gwxD[0] + a1v*gwxD[1] + a2v*gwxD[2] + a3v*gwxD[3]);
          sy[r] = rsum_1_8(a0v*gwyD[0] + a1v*gwyD[1] + a2v*gwyD[2] + a3v*gwyD[3]);
        }
        int rsel = l & 15;
        if (rsel < 4) {
          float4 stv;
          stv.x = sel4(s1[0], s1[1], s1[2], s1[3], rsel) * (1.f/64.f);
          stv.y = sel4(s2[0], s2[1], s2[2], s2[3], rsel) * (1.f/64.f);
          stv.z = sel4(sx[0], sx[1], sx[2], sx[3], rsel) * (1.f/64.f);
          stv.w = sel4(sy[0], sy[1], sy[2], sy[3], rsel) * (1.f/64.f);
          int frow = tile * 16 + (l >> 4) * 4 + rsel;
          *(float4*)(statsKV + (size_t)frow * 8 + mi * 4) = stv;
        }
        #pragma unroll
        for (int ct = 0; ct < 4; ++ct)
          #pragma unroll
          for (int r = 0; r < 4; ++r)
            tbuf[wave][(l >> 4) * 4 + r][ct * 16 + (l & 15)] = f2bf(acc[ct][r] * gfD[ct]);
        bf16x8 b0 = *(const bf16x8*)&tbuf[wave][l & 15][cb];
        bf16x8 b1 = *(const bf16x8*)&tbuf[wave][l & 15][32 + cb];
        f32x4 acc2[4];
        #pragma unroll
        for (int ct = 0; ct < 4; ++ct) acc2[ct] = (f32x4){0.f, 0.f, 0.f, 0.f};
        #pragma unroll
        for (int ct = 0; ct < 4; ++ct) {
          acc2[ct] = __builtin_amdgcn_mfma_f32_16x16x32_bf16(b0, wfrag[(5 * 8 + ct * 2 + 0) * 64 + l], acc2[ct], 0, 0, 0);
          acc2[ct] = __builtin_amdgcn_mfma_f32_16x16x32_bf16(b1, wfrag[(5 * 8 + ct * 2 + 1) * 64 + l], acc2[ct], 0, 0, 0);
        }
        if (mi == 0) {
          #pragma unroll
          for (int ct = 0; ct < 4; ++ct)
            #pragma unroll
            for (int r = 0; r < 4; ++r)
              tbuf[wave][(l >> 4) * 4 + r][ct * 16 + (l & 15)] = f2bf(acc2[ct][r]);
          u16x8 o0 = *(const u16x8*)&tbuf[wave][l & 15][cb];
          u16x8 o1 = *(const u16x8*)&tbuf[wave][l & 15][32 + cb];
          *(u16x8*)(A_k + (size_t)rowg * 64 + cb) = o0;
          *(u16x8*)(A_k + (size_t)rowg * 64 + 32 + cb) = o1;
        } else {
          int bb = tile >> 10;
          int nb4 = (tile * 16 + ((l >> 4) << 2)) & (Nn - 1);
          #pragma unroll
          for (int ct = 0; ct < 4; ++ct) {
            u16x4 u4;
            u4[0] = f2bf(acc2[ct][0]); u4[1] = f2bf(acc2[ct][1]);
            u4[2] = f2bf(acc2[ct][2]); u4[3] = f2bf(acc2[ct][3]);
            int d = ct * 16 + (l & 15);
            *(u16x4*)(A_vT + ((size_t)bb * 64 + d) * Nn + nb4) = u4;
          }
        }
      } else {
        #pragma unroll
        for (int ct = 0; ct < 4; ++ct)
          #pragma unroll
          for (int r = 0; r < 4; ++r) {
            int n = (tile * 16 + (l >> 4) * 4 + r) & (Nn - 1);
            acc[ct][r] += gwxD[ct] * gxf(n) + gwyD[ct] * gyf(n) + gbD[ct];
          }
        float mrow[4], rstd2[4];
        #pragma unroll
        for (int r = 0; r < 4; ++r) {
          float srow = acc[0][r] + acc[1][r] + acc[2][r] + acc[3][r];
          srow = rsum_1_8(srow);
          mrow[r] = srow * (1.f / 64.f);
          float vr = 0;
          #pragma unroll
          for (int ct = 0; ct < 4; ++ct) { float d = acc[ct][r] - mrow[r]; vr += d * d; }
          vr = rsum_1_8(vr);
          rstd2[r] = rsqrtf(vr * (1.f / 64.f) + 1e-5f);
        }
        #pragma unroll
        for (int ct = 0; ct < 4; ++ct)
          #pragma unroll
          for (int r = 0; r < 4; ++r)
            tbuf[wave][(l >> 4) * 4 + r][ct * 16 + (l & 15)] =
                f2bf((acc[ct][r] - mrow[r]) * rstd2[r] * mlgD[ct] + mlbD[ct]);
        bf16x8 b0 = *(const bf16x8*)&tbuf[wave][l & 15][cb];
        bf16x8 b1 = *(const bf16x8*)&tbuf[wave][l & 15][32 + cb];
        f32x4 acc2[4];
        #pragma unroll
        for (int ct = 0; ct < 4; ++ct) acc2[ct] = (f32x4){0.f, 0.f, 0.f, 0.f};
        #pragma unroll
        for (int ct = 0; ct < 4; ++ct) {
          acc2[ct] = __builtin_amdgcn_mfma_f32_16x16x32_bf16(b0, wfrag[(4 * 8 + ct * 2 + 0) * 64 + l], acc2[ct], 0, 0, 0);
          acc2[ct] = __builtin_amdgcn_mfma_f32_16x16x32_bf16(b1, wfrag[(4 * 8 + ct * 2 + 1) * 64 + l], acc2[ct], 0, 0, 0);
        }
        #pragma unroll
        for (int ct = 0; ct < 4; ++ct)
          #pragma unroll
          for (int r = 0; r < 4; ++r)
            tbuf[wave][(l >> 4) * 4 + r][ct * 16 + (l & 15)] = f2bf(acc2[ct][r] + mbbD[ct]);
        unsigned short* dst = (mi == 2) ? kbg : vbg;
        u16x8 o0 = *(const u16x8*)&tbuf[wave][l & 15][cb];
        u16x8 o1 = *(const u16x8*)&tbuf[wave][l & 15][32 + cb];
        *(u16x8*)(dst + (size_t)rowg * 64 + cb) = o0;
        *(u16x8*)(dst + (size_t)rowg * 64 + 32 + cb) = o1;
      }
    }
  }
}

// ---------------------------------------------------------------- k_iter
// it==0: q from prep buffers. it>=1: in-block redundant combine of previous
// iteration partials (double-buffered; no intra-launch cross-block comms).
__global__ __launch_bounds__(256) void k_iter(
    int it,
    const unsigned short* __restrict__ A_k, const unsigned short* __restrict__ A_vT,
    const float* __restrict__ statsKV,
    const unsigned short* __restrict__ kbg, const unsigned short* __restrict__ vbg,
    const float* __restrict__ q_fg0, const float* __restrict__ q_bg0,
    const float* __restrict__ fg_pos0, const float* __restrict__ mask,
    const float* __restrict__ cbuf,
    const float* __restrict__ fgP_r, float* __restrict__ fgP_w,
    const float* __restrict__ bgP_r, float* __restrict__ bgP_w,
    const float* __restrict__ slotfg_r, float* __restrict__ slotfg_w,
    const float* __restrict__ slotbg_r, float* __restrict__ slotbg_w,
    const float* __restrict__ gfg_wih, const float* __restrict__ gfg_whh,
    const float* __restrict__ gfg_bih, const float* __restrict__ gfg_bhh,
    const float* __restrict__ gbg_wih, const float* __restrict__ gbg_whh,
    const float* __restrict__ gbg_bih, const float* __restrict__ gbg_bhh,
    const float* __restrict__ rfg_g, const float* __restrict__ rfg_b2,
    const float* __restrict__ rfg_w, const float* __restrict__ rfg_bb,
    const float* __restrict__ rbg_g, const float* __restrict__ rbg_b2,
    const float* __restrict__ rbg_w, const float* __restrict__ rbg_bb,
    const float* __restrict__ qln_g, const float* __restrict__ qln_b, const float* __restrict__ qw,
    const float* __restrict__ qbgln_g, const float* __restrict__ qbgln_b, const float* __restrict__ qbgw)
{
  __shared__ float qa_pl[4][260];
  __shared__ __align__(16) unsigned short w_buf[4][272];
  __shared__ float redv[4][4][64];
  __shared__ float shred[4][130];
  __shared__ float xsw[4][64], hsw[4][64];
  __shared__ float qsh[4][64];
  int tid = threadIdx.x, wave = tid >> 6, l = tid & 63;
  if ((int)blockIdx.x < FG_BLK) {
    int b = blockIdx.x >> 6, ch = blockIdx.x & 63;
    int n0 = ch * CH;
    int w = wave;
    float px, py, qGx, qGy, qgW, qC0;
    if (it == 0) {
      float qv = q_fg0[(b * 4 + w) * 64 + l];
      qsh[w][l] = qv;
      qGx = rsum_all(qv * cbuf[l]);
      qGy = rsum_all(qv * cbuf[64 + l]);
      qgW = rsum_all(qv * cbuf[128 + l]);
      qC0 = rsum_all(qv * cbuf[192 + l]);
      px = fg_pos0[(b * 4 + w) * 2 + 0];
      py = fg_pos0[(b * 4 + w) * 2 + 1];
      __syncthreads();
    } else {
      // ---- redundant combine of iteration it-1, slot w (wave-local)
      const float* Pb = fgP_r + ((size_t)(b * 64 + l) * 4 + w) * FG_PS;
      float mp = Pb[0], sp = Pb[1], pxp = Pb[2], pyp = Pb[3];
      float sxp = Pb[4], syp = Pb[5], smp = Pb[6];
      float mg = rmax_all(mp);
      float wgt = __expf(mp - mg);
      float S = rsum_all(wgt * sp);
      px = rsum_all(wgt * pxp) / S;
      py = rsum_all(wgt * pyp) / S;
      float sxg = rsum_all(wgt * sxp);
      float syg = rsum_all(wgt * syp);
      float smg = rsum_all(wgt * smp);
      float ua = 0;
      #pragma unroll 8
      for (int c = 0; c < 64; ++c) {
        float wc = __shfl(wgt, c);
        ua += wc * fgP_r[((size_t)(b * 64 + c) * 4 + w) * FG_PS + 8 + l];
      }
      float upd = (ua + sxg * cbuf[l] + syg * cbuf[64 + l] - smg * cbuf[128 + l]) / S + cbuf[192 + l];
      float h = slotfg_r[(b * 4 + w) * 64 + l];
      xsw[w][l] = upd; hsw[w][l] = h;
      __syncthreads();
      float gir = gfg_bih[l], giz = gfg_bih[64 + l], gin = gfg_bih[128 + l];
      float ghr = gfg_bhh[l], ghz = gfg_bhh[64 + l], ghn = gfg_bhh[128 + l];
      #pragma unroll 8
      for (int c = 0; c < 64; ++c) {
        float u = xsw[w][c], hh = hsw[w][c];
        gir += gfg_wih[l * 64 + c] * u;
        giz += gfg_wih[(64 + l) * 64 + c] * u;
        gin += gfg_wih[(128 + l) * 64 + c] * u;
        ghr += gfg_whh[l * 64 + c] * hh;
        ghz += gfg_whh[(64 + l) * 64 + c] * hh;
        ghn += gfg_whh[(128 + l) * 64 + c] * hh;
      }
      float r = sigm(gir + ghr), z = sigm(giz + ghz);
      float nng = tanhf(gin + r * ghn);
      float hnew = (1.f - z) * nng + z * h;
      float mean = rsum_all(hnew) * (1.f / 64.f);
      float d = hnew - mean;
      float var = rsum_all(d * d) * (1.f / 64.f);
      float lnv = d * rsqrtf(var + 1e-5f) * rfg_g[l] + rfg_b2[l];
      __syncthreads();
      xsw[w][l] = lnv;
      __syncthreads();
      float acc2 = 0;
      #pragma unroll 8
      for (int c = 0; c < 64; ++c) acc2 += rfg_w[l * 64 + c] * xsw[w][c];
      float snew = acc2 + rfg_bb[l] + h;
      if (ch == 0) slotfg_w[(b * 4 + w) * 64 + l] = snew;
      float mq = rsum_all(snew) * (1.f / 64.f);
      float dq = snew - mq;
      float vq = rsum_all(dq * dq) * (1.f / 64.f);
      float lnq = dq * rsqrtf(vq + 1e-5f) * qln_g[l] + qln_b[l];
      __syncthreads();
      xsw[w][l] = lnq;
      __syncthreads();
      float qacc = 0;
      #pragma unroll 8
      for (int c = 0; c < 64; ++c) qacc += qw[l * 64 + c] * xsw[w][c];
      qsh[w][l] = qacc;
      qGx = rsum_all(qacc * cbuf[l]);
      qGy = rsum_all(qacc * cbuf[64 + l]);
      qgW = rsum_all(qacc * cbuf[128 + l]);
      qC0 = rsum_all(qacc * cbuf[192 + l]);
      __syncthreads();
    }
    // build q A-frags from qsh
    int slot = l & 15;
    bf16x8 qf0, qf1;
    {
      int bkq = slot & 3;
      #pragma unroll
      for (int j = 0; j < 8; ++j) {
        float v0 = qsh[bkq][(l >> 4) * 8 + j];
        float v1 = qsh[bkq][32 + (l >> 4) * 8 + j];
        qf0[j] = (short)f2bf(slot < 4 ? v0 : 0.f);
        qf1[j] = (short)f2bf(slot < 4 ? v1 : 0.f);
      }
    }
    // phase 0: qA = q @ A_k^T
    #pragma unroll
    for (int tt2 = 0; tt2 < 4; ++tt2) {
      int t = wave * 4 + tt2;
      const unsigned short* ap = A_k + ((size_t)b * Nn + n0 + t * 16 + (l & 15)) * 64 + ((l >> 4) << 3);
      bf16x8 b0 = *(const bf16x8*)ap;
      bf16x8 b1 = *(const bf16x8*)(ap + 32);
      f32x4 acc = (f32x4){0.f, 0.f, 0.f, 0.f};
      acc = __builtin_amdgcn_mfma_f32_16x16x32_bf16(qf0, b0, acc, 0, 0, 0);
      acc = __builtin_amdgcn_mfma_f32_16x16x32_bf16(qf1, b1, acc, 0, 0, 0);
      if (l < 16) {
        #pragma unroll
        for (int r = 0; r < 4; ++r) qa_pl[r][t * 16 + l] = acc[r];
      }
    }
    __syncthreads();
    // phase A
    float mgx = cbuf[256], mgy = cbuf[257], egx2 = cbuf[258], egy2 = cbuf[259], egxy = cbuf[260];
    float lgc[4], rsv[4], muvc[4];
    float mx = NEGINF;
    #pragma unroll
    for (int i = 0; i < 4; ++i) {
      int n = n0 + i * 64 + l;
      const float* st = statsKV + ((size_t)b * Nn + n) * 8;
      float4 sk = *(const float4*)st;
      float4 sv = *(const float4*)(st + 4);
      float gx = gxf(n), gy = gyf(n);
      float relx = gx - px, rely = gy - py;
      float mu = sk.x + relx * mgx + rely * mgy;
      float ex2 = sk.y + 2.f*(relx*sk.z + rely*sk.w) + relx*relx*egx2 + rely*rely*egy2 + 2.f*relx*rely*egxy;
      float rstd = rsqrtf(fmaxf(ex2 - mu * mu, 0.f) + 1e-5f);
      float qa = qa_pl[w][i * 64 + l];
      float lg = 0.125f * (rstd * (qa + relx * qGx + rely * qGy - mu * qgW) + qC0);
      float mk = mask[w * Nn + n];
      lg = (mk == 0.f) ? -1e9f : lg;
      lgc[i] = lg; mx = fmaxf(mx, lg);
      float muv = sv.x + relx * mgx + rely * mgy;
      float ex2v = sv.y + 2.f*(relx*sv.z + rely*sv.w) + relx*relx*egx2 + rely*rely*egy2 + 2.f*relx*rely*egxy;
      rsv[i] = rsqrtf(fmaxf(ex2v - muv * muv, 0.f) + 1e-5f);
      muvc[i] = muv;
    }
    float mb = rmax_all(mx);
    float s_a = 0, px_a = 0, py_a = 0, swx = 0, swy = 0, swm = 0;
    #pragma unroll
    for (int i = 0; i < 4; ++i) {
      int n = n0 + i * 64 + l;
      float e = __expf(lgc[i] - mb);
      float gx = gxf(n), gy = gyf(n);
      s_a += e; px_a += e * gx; py_a += e * gy;
      float wgt2 = e * rsv[i];
      swx += wgt2 * (gx - px); swy += wgt2 * (gy - py); swm += wgt2 * muvc[i];
      w_buf[w][i * 64 + l] = f2bf(wgt2);
    }
    s_a = rsum_all(s_a); px_a = rsum_all(px_a); py_a = rsum_all(py_a);
    swx = rsum_all(swx); swy = rsum_all(swy); swm = rsum_all(swm);
    if (l == 0) {
      float* P = fgP_w + ((size_t)(b * NCH + ch) * 4 + w) * FG_PS;
      P[0] = mb; P[1] = s_a; P[2] = px_a; P[3] = py_a; P[4] = swx; P[5] = swy; P[6] = swm;
    }
    __syncthreads();
    // phase B
    f32x4 acc[4];
    #pragma unroll
    for (int ct = 0; ct < 4; ++ct) acc[ct] = (f32x4){0.f, 0.f, 0.f, 0.f};
    bf16x8 zz;
    #pragma unroll
    for (int j = 0; j < 8; ++j) zz[j] = 0;
    #pragma unroll
    for (int st2 = 0; st2 < 2; ++st2) {
      int noff = wave * 64 + st2 * 32;
      bf16x8 wf = *(const bf16x8*)&w_buf[l & 3][noff + ((l >> 4) << 3)];
      if ((l & 15) >= 4) wf = zz;
      #pragma unroll
      for (int ct = 0; ct < 4; ++ct) {
        const unsigned short* ap = A_vT + ((size_t)b * 64 + ct * 16 + (l & 15)) * Nn + n0 + noff + ((l >> 4) << 3);
        bf16x8 bv = *(const bf16x8*)ap;
        acc[ct] = __builtin_amdgcn_mfma_f32_16x16x32_bf16(wf, bv, acc[ct], 0, 0, 0);
      }
    }
    if (l < 16) {
      #pragma unroll
      for (int ct = 0; ct < 4; ++ct)
        #pragma unroll
        for (int r = 0; r < 4; ++r)
          redv[wave][r][ct * 16 + l] = acc[ct][r];
    }
    __syncthreads();
    if (wave == 0) {
      #pragma unroll
      for (int s2 = 0; s2 < 4; ++s2) {
        float v = redv[0][s2][l] + redv[1][s2][l] + redv[2][s2][l] + redv[3][s2][l];
        fgP_w[((size_t)(b * NCH + ch) * 4 + s2) * FG_PS + 8 + l] = v;
      }
    }
  } else {
    int idx = blockIdx.x - FG_BLK;
    int b = idx >> 6, nb = idx & 63;
    int cb16 = (l >> 4) << 4;
    float qr[16];
    if (it == 0) {
      #pragma unroll
      for (int i = 0; i < 16; ++i) qr[i] = q_bg0[b * 64 + cb16 + i];
    } else {
      // ---- redundant bg combine of iteration it-1
      __shared__ float wlb[64];
      __shared__ float scS;
      __shared__ float xsb[64], hsb2[64], qshbg[64];
      if (wave == 0) {
        const float* pbp = bgP_r + (size_t)(b * NBG + l) * BG_PS;
        float mp = pbp[0], sp = pbp[1];
        float mg = rmax_all(mp);
        float wgt = __expf(mp - mg);
        wlb[l] = wgt;
        float S = rsum_all(wgt * sp);
        if (l == 0) scS = S;
      }
      __syncthreads();
      float acc = 0, sva = 0;
      #pragma unroll
      for (int i = 0; i < 16; ++i) {
        int p = wave * 16 + i;
        acc += wlb[p] * bgP_r[(size_t)(b * NBG + p) * BG_PS + 2 + l];
        sva += bgP_r[(size_t)(b * NBG + p) * BG_PS + 66 + l];
      }
      shred[wave][l] = acc; shred[wave][66 + l] = sva;
      __syncthreads();
      if (wave == 0) {
        float upd = (shred[0][l] + shred[1][l] + shred[2][l] + shred[3][l]) / scS
                  + 1e-8f * (shred[0][66 + l] + shred[1][66 + l] + shred[2][66 + l] + shred[3][66 + l]);
        float h = slotbg_r[b * 64 + l];
        xsb[l] = upd; hsb2[l] = h;
      }
      __syncthreads();
      if (wave == 0) {
        float h = hsb2[l];
        float gir = gbg_bih[l], giz = gbg_bih[64 + l], gin = gbg_bih[128 + l];
        float ghr = gbg_bhh[l], ghz = gbg_bhh[64 + l], ghn = gbg_bhh[128 + l];
        #pragma unroll 8
        for (int c = 0; c < 64; ++c) {
          float u = xsb[c], hh = hsb2[c];
          gir += gbg_wih[l * 64 + c] * u;
          giz += gbg_wih[(64 + l) * 64 + c] * u;
          gin += gbg_wih[(128 + l) * 64 + c] * u;
          ghr += gbg_whh[l * 64 + c] * hh;
          ghz += gbg_whh[(64 + l) * 64 + c] * hh;
          ghn += gbg_whh[(128 + l) * 64 + c] * hh;
        }
        float r = sigm(gir + ghr), z = sigm(giz + ghz);
        float nng = tanhf(gin + r * ghn);
        float hnew = (1.f - z) * nng + z * h;
        float mean = rsum_all(hnew) * (1.f / 64.f);
        float d = hnew - mean;
        float var = rsum_all(d * d) * (1.f / 64.f);
        xsb[l] = d * rsqrtf(var + 1e-5f) * rbg_g[l] + rbg_b2[l];
      }
      __syncthreads();
      if (wave == 0) {
        float h = hsb2[l];
        float acc2 = 0;
        #pragma unroll 8
        for (int c = 0; c < 64; ++c) acc2 += rbg_w[l * 64 + c] * xsb[c];
        float snew = acc2 + rbg_bb[l] + h;
        if (nb == 0) slotbg_w[b * 64 + l] = snew;
        float mq = rsum_all(snew) * (1.f / 64.f);
        float dq = snew - mq;
        float vq = rsum_all(dq * dq) * (1.f / 64.f);
        hsb2[l] = dq * rsqrtf(vq + 1e-5f) * qbgln_g[l] + qbgln_b[l];
      }
      __syncthreads();
      if (wave == 0) {
        float qacc = 0;
        #pragma unroll 8
        for (int c = 0; c < 64; ++c) qacc += qbgw[l * 64 + c] * hsb2[c];
        qshbg[l] = qacc;
      }
      __syncthreads();
      #pragma unroll
      for (int i = 0; i < 16; ++i) qr[i] = qshbg[cb16 + i];
      __syncthreads();
    }
    float m = NEGINF, s = 0.f, upd[16], sv[16];
    #pragma unroll
    for (int i = 0; i < 16; ++i) { upd[i] = 0; sv[i] = 0; }
    #pragma unroll
    for (int pass = 0; pass < 4; ++pass) {
      int nrow = nb * 256 + pass * 64 + wave * 16 + (l & 15);
      const unsigned short* kp = kbg + ((size_t)b * Nn + nrow) * 64 + cb16;
      const unsigned short* vp = vbg + ((size_t)b * Nn + nrow) * 64 + cb16;
      u16x8 k0 = *(const u16x8*)kp, k1 = *(const u16x8*)(kp + 8);
      u16x8 v0 = *(const u16x8*)vp, v1 = *(const u16x8*)(vp + 8);
      float p = 0;
      #pragma unroll
      for (int i = 0; i < 8; ++i) { p += qr[i] * bf2f(k0[i]); p += qr[8 + i] * bf2f(k1[i]); }
      p = rsum_16_32(p);
      float lg = 0.125f * p;
      float tm = rmax_1_8(lg);
      float mnew = fmaxf(m, tm);
      float alpha = __expf(m - mnew); m = mnew;
      s *= alpha;
      #pragma unroll
      for (int i = 0; i < 16; ++i) upd[i] *= alpha;
      float e = __expf(lg - mnew);
      s += e;
      #pragma unroll
      for (int i = 0; i < 8; ++i) {
        float fv0 = bf2f(v0[i]), fv1 = bf2f(v1[i]);
        upd[i] += e * fv0; upd[8 + i] += e * fv1;
        sv[i] += fv0; sv[8 + i] += fv1;
      }
    }
    s = rsum_1_8(s);
    #pragma unroll
    for (int i = 0; i < 16; ++i) { upd[i] = rsum_1_8(upd[i]); sv[i] = rsum_1_8(sv[i]); }
    if (l == 0) { shred[wave][0] = m; shred[wave][1] = s; }
    if ((l & 15) == 0) {
      int g = l >> 4;
      #pragma unroll
      for (int i = 0; i < 16; ++i) { shred[wave][2 + g * 16 + i] = upd[i]; shred[wave][66 + g * 16 + i] = sv[i]; }
    }
    __syncthreads();
    if (wave == 0) {
      float m0 = shred[0][0], m1 = shred[1][0], m2 = shred[2][0], m3 = shred[3][0];
      float mg = fmaxf(fmaxf(m0, m1), fmaxf(m2, m3));
      float w0 = __expf(m0 - mg), w1 = __expf(m1 - mg), w2 = __expf(m2 - mg), w3 = __expf(m3 - mg);
      float* P = bgP_w + (size_t)idx * BG_PS;
      P[2 + l]  = w0 * shred[0][2 + l] + w1 * shred[1][2 + l] + w2 * shred[2][2 + l] + w3 * shred[3][2 + l];
      P[66 + l] = shred[0][66 + l] + shred[1][66 + l] + shred[2][66 + l] + shred[3][66 + l];
      if (l == 0) {
        P[0] = mg;
        P[1] = w0 * shred[0][1] + w1 * shred[1][1] + w2 * shred[2][1] + w3 * shred[3][1];
      }
    }
  }
}

// ---------------------------------------------------------------- k_fin (final combine + dout)
__global__ __launch_bounds__(256) void k_fin(
    const float* __restrict__ fgP, const float* __restrict__ bgP,
    const float* __restrict__ slotfg, const float* __restrict__ slotbg,
    const float* __restrict__ cbuf,
    const float* __restrict__ gfg_wih, const float* __restrict__ gfg_whh,
    const float* __restrict__ gfg_bih, const float* __restrict__ gfg_bhh,
    const float* __restrict__ gbg_wih, const float* __restrict__ gbg_whh,
    const float* __restrict__ gbg_bih, const float* __restrict__ gbg_bhh,
    const float* __restrict__ rfg_g, const float* __restrict__ rfg_b2,
    const float* __restrict__ rfg_w, const float* __restrict__ rfg_bb,
    const float* __restrict__ rbg_g, const float* __restrict__ rbg_b2,
    const float* __restrict__ rbg_w, const float* __restrict__ rbg_bb,
    float* __restrict__ dout)
{
  __shared__ float wl[64];
  __shared__ float ubuf[4][64];
  __shared__ float part[4][64];
  __shared__ float xs[64], hs[64];
  __shared__ float gd[384];
  __shared__ float scal[6];
  int tid = threadIdx.x, wv = tid >> 6, l = tid & 63;
  int blk = blockIdx.x;
  if (blk < 16) {
    int bk = blk, b = bk >> 2, k = bk & 3;
    if (wv == 0) {
      const float* pp = fgP + ((size_t)(b * NCH + l) * 4 + k) * FG_PS;
      float mp = pp[0], sp = pp[1], pxp = pp[2], pyp = pp[3];
      float sxp = pp[4], syp = pp[5], smp = pp[6];
      float mg = rmax_all(mp);
      float w = __expf(mp - mg);
      wl[l] = w;
      float S = rsum_all(w * sp);
      float px = rsum_all(w * pxp);
      float py = rsum_all(w * pyp);
      float sxg = rsum_all(w * sxp);
      float syg = rsum_all(w * syp);
      float smg = rsum_all(w * smp);
      if (l == 0) { scal[0]=S; scal[1]=px/S; scal[2]=py/S; scal[3]=sxg; scal[4]=syg; scal[5]=smg; }
    }
    __syncthreads();
    float S = scal[0];
    float acc = 0;
    #pragma unroll
    for (int i = 0; i < 16; ++i) {
      int c = wv * 16 + i;
      acc += wl[c] * fgP[((size_t)(b * NCH + c) * 4 + k) * FG_PS + 8 + l];
    }
    ubuf[wv][l] = acc;
    __syncthreads();
    if (wv == 0) {
      float UV = ubuf[0][l] + ubuf[1][l] + ubuf[2][l] + ubuf[3][l];
      float upd = (UV + scal[3] * cbuf[l] + scal[4] * cbuf[64 + l] - scal[5] * cbuf[128 + l]) / S + cbuf[192 + l];
      xs[l] = upd;
      hs[l] = slotfg[bk * 64 + l];
    }
    __syncthreads();
    {
      int r = tid;
      float a;
      if (r < 192) {
        const float* w = gfg_wih + r * 64; a = gfg_bih[r];
        #pragma unroll 8
        for (int c = 0; c < 64; ++c) a += w[c] * xs[c];
      } else {
        const float* w = gfg_whh + (r - 192) * 64; a = gfg_bhh[r - 192];
        #pragma unroll 8
        for (int c = 0; c < 64; ++c) a += w[c] * hs[c];
      }
      gd[r] = a;
      if (tid < 128) {
        int r2 = tid + 256;
        const float* w = gfg_whh + (r2 - 192) * 64; float a2 = gfg_bhh[r2 - 192];
        #pragma unroll 8
        for (int c = 0; c < 64; ++c) a2 += w[c] * hs[c];
        gd[r2] = a2;
      }
    }
    __syncthreads();
    if (wv == 0) {
      float h = hs[l];
      float r = sigm(gd[l] + gd[192 + l]);
      float z = sigm(gd[64 + l] + gd[256 + l]);
      float nng = tanhf(gd[128 + l] + r * gd[320 + l]);
      float hnew = (1.f - z) * nng + z * h;
      float mean = rsum_all(hnew) * (1.f / 64.f);
      float d = hnew - mean;
      float var = rsum_all(d * d) * (1.f / 64.f);
      xs[l] = d * rsqrtf(var + 1e-5f) * rfg_g[l] + rfg_b2[l];
    }
    __syncthreads();
    {
      int c0 = wv * 16;
      const float* w = rfg_w + l * 64 + c0;
      float a = 0;
      #pragma unroll
      for (int c = 0; c < 16; ++c) a += w[c] * xs[c0 + c];
      part[wv][l] = a;
    }
    __syncthreads();
    if (wv == 0) {
      float snew = part[0][l] + part[1][l] + part[2][l] + part[3][l] + rfg_bb[l] + hs[l];
      dout[(b * 5 + 1 + k) * 64 + l] = snew;
      if (l == 0) {
        dout[1280 + bk * 2 + 0] = scal[1];
        dout[1280 + bk * 2 + 1] = scal[2];
      }
    }
  } else {
    int b = blk - 16;
    const float* P = bgP + (size_t)b * NBG * BG_PS;
    if (wv == 0) {
      float mp = P[l * BG_PS + 0];
      float sp = P[l * BG_PS + 1];
      float mg = rmax_all(mp);
      float w = __expf(mp - mg);
      wl[l] = w;
      float S = rsum_all(w * sp);
      if (l == 0) scal[0] = S;
    }
    __syncthreads();
    float S = scal[0];
    float acc = 0, sva = 0;
    #pragma unroll
    for (int i = 0; i < 16; ++i) {
      int p = wv * 16 + i;
      acc += wl[p] * P[(size_t)p * BG_PS + 2 + l];
      sva += P[(size_t)p * BG_PS + 66 + l];
    }
    ubuf[wv][l] = acc; part[wv][l] = sva;
    __syncthreads();
    if (wv == 0) {
      float upd = (ubuf[0][l] + ubuf[1][l] + ubuf[2][l] + ubuf[3][l]) / S
                + 1e-8f * (part[0][l] + part[1][l] + part[2][l] + part[3][l]);
      xs[l] = upd;
      hs[l] = slotbg[b * 64 + l];
    }
    __syncthreads();
    {
      int r = tid;
      float a;
      if (r < 192) {
        const float* w = gbg_wih + r * 64; a = gbg_bih[r];
        #pragma unroll 8
        for (int c = 0; c < 64; ++c) a += w[c] * xs[c];
      } else {
        const float* w = gbg_whh + (r - 192) * 64; a = gbg_bhh[r - 192];
        #pragma unroll 8
        for (int c = 0; c < 64; ++c) a += w[c] * hs[c];
      }
      gd[r] = a;
      if (tid < 128) {
        int r2 = tid + 256;
        const float* w = gbg_whh + (r2 - 192) * 64; float a2 = gbg_bhh[r2 - 192];
        #pragma unroll 8
        for (int c = 0; c < 64; ++c) a2 += w[c] * hs[c];
        gd[r2] = a2;
      }
    }
    __syncthreads();
    if (wv == 0) {
      float h = hs[l];
      float r = sigm(gd[l] + gd[192 + l]);
      float z = sigm(gd[64 + l] + gd[256 + l]);
      float nng = tanhf(gd[128 + l] + r * gd[320 + l]);
      float hnew = (1.f - z) * nng + z * h;
      float mean = rsum_all(hnew) * (1.f / 64.f);
      float d = hnew - mean;
      float var = rsum_all(d * d) * (1.f / 64.f);
      xs[l] = d * rsqrtf(var + 1e-5f) * rbg_g[l] + rbg_b2[l];
    }
    __syncthreads();
    {
      int c0 = wv * 16;
      const float* w = rbg_w + l * 64 + c0;
      float a = 0;
      #pragma unroll
      for (int c = 0; c < 16; ++c) a += w[c] * xs[c0 + c];
      part[wv][l] = a;
    }
    __syncthreads();
    if (wv == 0) {
      float snew = part[0][l] + part[1][l] + part[2][l] + part[3][l] + rbg_bb[l] + hs[l];
      dout[(b * 5 + 0) * 64 + l] = snew;
    }
  }
}

// ---------------------------------------------------------------- launch
extern "C" void kernel_launch(void* const* d_in, const int* in_sizes, int n_in,
                              void* d_out, int out_size, void* d_ws, size_t ws_size,
                              hipStream_t stream)
{
  (void)in_sizes; (void)n_in; (void)out_size; (void)ws_size;
  const float* feat        = (const float*)d_in[0];
  const float* mask        = (const float*)d_in[1];
  const float* noise_fg    = (const float*)d_in[2];
  const float* noise_bg    = (const float*)d_in[3];
  const float* slots_mu    = (const float*)d_in[4];
  const float* slots_ls    = (const float*)d_in[5];
  const float* slots_mu_bg = (const float*)d_in[6];
  const float* slots_ls_bg = (const float*)d_in[7];
  const float* norm_feat_g = (const float*)d_in[8];
  const float* norm_feat_b = (const float*)d_in[9];
  const float* grid_embed_w= (const float*)d_in[10];
  const float* grid_embed_b= (const float*)d_in[11];
  const float* k_fg_w      = (const float*)d_in[12];
  const float* v_fg_w      = (const float*)d_in[13];
  const float* k_bg_w      = (const float*)d_in[14];
  const float* v_bg_w      = (const float*)d_in[15];
  const float* mlp_fg_ln_g = (const float*)d_in[16];
  const float* mlp_fg_ln_b = (const float*)d_in[17];
  const float* mlp_fg_w    = (const float*)d_in[18];
  const float* mlp_fg_b    = (const float*)d_in[19];
  const float* mlp_bg_ln_g = (const float*)d_in[20];
  const float* mlp_bg_ln_b = (const float*)d_in[21];
  const float* mlp_bg_w    = (const float*)d_in[22];
  const float* mlp_bg_b    = (const float*)d_in[23];
  const float* q_ln_g      = (const float*)d_in[24];
  const float* q_ln_b      = (const float*)d_in[25];
  const float* q_w         = (const float*)d_in[26];
  const float* qbg_ln_g    = (const float*)d_in[27];
  const float* qbg_ln_b    = (const float*)d_in[28];
  const float* qbg_w       = (const float*)d_in[29];
  const float* gru_fg_wih  = (const float*)d_in[30];
  const float* gru_fg_whh  = (const float*)d_in[31];
  const float* gru_fg_bih  = (const float*)d_in[32];
  const float* gru_fg_bhh  = (const float*)d_in[33];
  const float* gru_bg_wih  = (const float*)d_in[34];
  const float* gru_bg_whh  = (const float*)d_in[35];
  const float* gru_bg_bih  = (const float*)d_in[36];
  const float* gru_bg_bhh  = (const float*)d_in[37];
  const float* res_fg_ln_g = (const float*)d_in[38];
  const float* res_fg_ln_b = (const float*)d_in[39];
  const float* res_fg_w    = (const float*)d_in[40];
  const float* res_fg_b    = (const float*)d_in[41];
  const float* res_bg_ln_g = (const float*)d_in[42];
  const float* res_bg_ln_b = (const float*)d_in[43];
  const float* res_bg_w    = (const float*)d_in[44];
  const float* res_bg_b    = (const float*)d_in[45];
  float* dout = (float*)d_out;

  char* wsp = (char*)d_ws;
  size_t off = 0;
  auto alloc = [&](size_t bytes) -> void* {
    void* p = wsp + off;
    off += (bytes + 255) & ~(size_t)255;
    return p;
  };
  unsigned short* A_k  = (unsigned short*)alloc((size_t)Bb * Nn * 64 * 2);
  unsigned short* A_vT = (unsigned short*)alloc((size_t)Bb * Nn * 64 * 2);
  float* statsKV       = (float*)alloc((size_t)Bb * Nn * 8 * 4);
  unsigned short* kbg  = (unsigned short*)alloc((size_t)Bb * Nn * 64 * 2);
  unsigned short* vbg  = (unsigned short*)alloc((size_t)Bb * Nn * 64 * 2);
  float* sfg[2]; float* sbg[2]; float* fgP[2]; float* bgP[2];
  sfg[0] = (float*)alloc(16 * 64 * 4); sfg[1] = (float*)alloc(16 * 64 * 4);
  sbg[0] = (float*)alloc(4 * 64 * 4);  sbg[1] = (float*)alloc(4 * 64 * 4);
  float* q_fg    = (float*)alloc(16 * 64 * 4);
  float* q_bg    = (float*)alloc(4 * 64 * 4);
  float* fg_pos  = (float*)alloc(16 * 2 * 4);
  float* cbuf    = (float*)alloc(264 * 4);
  fgP[0] = (float*)alloc((size_t)Bb * NCH * 4 * FG_PS * 4);
  fgP[1] = (float*)alloc((size_t)Bb * NCH * 4 * FG_PS * 4);
  bgP[0] = (float*)alloc((size_t)BG_BLK * BG_PS * 4);
  bgP[1] = (float*)alloc((size_t)BG_BLK * BG_PS * 4);

  k_prep<<<1049, 256, 0, stream>>>(feat, norm_feat_g, norm_feat_b, grid_embed_w, grid_embed_b,
                                   k_fg_w, v_fg_w, k_bg_w, v_bg_w,
                                   mlp_bg_ln_g, mlp_bg_ln_b, mlp_bg_w, mlp_bg_b,
                                   mlp_fg_ln_g, mlp_fg_ln_b, mlp_fg_w, mlp_fg_b, mask,
                                   A_k, A_vT, statsKV, kbg, vbg,
                                   noise_fg, noise_bg, slots_mu, slots_ls, slots_mu_bg, slots_ls_bg,
                                   q_ln_g, q_ln_b, q_w, qbg_ln_g, qbg_ln_b, qbg_w,
                                   sfg[0], sbg[0], q_fg, q_bg, fg_pos, cbuf);
  for (int it = 0; it < 4; ++it) {
    int pr = (it + 1) & 1;   // read parity (it-1)&1
    int pw = it & 1;         // write parity
    k_iter<<<FG_BLK + BG_BLK, 256, 0, stream>>>(it, A_k, A_vT, statsKV, kbg, vbg,
                                                q_fg, q_bg, fg_pos, mask, cbuf,
                                                fgP[pr], fgP[pw], bgP[pr], bgP[pw],
                                                sfg[pr], sfg[pw], sbg[pr], sbg[pw],
                                                gru_fg_wih, gru_fg_whh, gru_fg_bih, gru_fg_bhh,
                                                gru_bg_wih, gru_bg_whh, gru_bg_bih, gru_bg_bhh,
                                                res_fg_ln_g, res_fg_ln_b, res_fg_w, res_fg_b,
                                                res_bg_ln_g, res_bg_ln_b, res_bg_w, res_bg_b,
                                                q_ln_g, q_ln_b, q_w, qbg_ln_g, qbg_ln_b, qbg_w);
  }
  k_fin<<<20, 256, 0, stream>>>(fgP[1], bgP[1], sfg[1], sbg[1], cbuf,
                                gru_fg_wih, gru_fg_whh, gru_fg_bih, gru_fg_bhh,
                                gru_bg_wih, gru_bg_whh, gru_bg_bih, gru_bg_bhh,
                                res_fg_ln_g, res_fg_ln_b, res_fg_w, res_fg_b,
                                res_bg_ln_g, res_bg_ln_b, res_bg_w, res_bg_b,
                                dout);
}

// Round 7
// 112.834 us; speedup vs baseline: 1.4205x; 1.4205x over previous
//
#include <hip/hip_runtime.h>
#include <math.h>

#define DEVI __device__ __forceinline__

constexpr int Bb = 4, Nn = 16384, Kk = 4;
constexpr int NCH = 64;                  // fg chunks per b
constexpr int CH = 256;                  // n per fg chunk
constexpr int FG_BLK = Bb * NCH;         // 256
constexpr int NBG = 64;                  // bg chunks per b
constexpr int BG_BLK = Bb * NBG;         // 256
constexpr int FG_PS = 72;                // m,s,px,py,swx,swy,swm,pad,upd[64]
constexpr int BG_PS = 130;               // m,s,upd[64],sumv[64]
constexpr int NT = Nn / 16;              // 1024 n-tiles per b

typedef __attribute__((ext_vector_type(8))) short bf16x8;
typedef __attribute__((ext_vector_type(8))) unsigned short u16x8;
typedef __attribute__((ext_vector_type(4))) unsigned short u16x4;
typedef __attribute__((ext_vector_type(4))) float f32x4;

DEVI float bf2f(unsigned short u){ unsigned int x = ((unsigned int)u) << 16; return __builtin_bit_cast(float, x); }
DEVI unsigned short f2bf(float f){
  unsigned int u = __builtin_bit_cast(unsigned int, f);
  u += 0x7fffu + ((u >> 16) & 1u);
  return (unsigned short)(u >> 16);
}
DEVI float rsum_16_32(float v){ v += __shfl_xor(v,16); v += __shfl_xor(v,32); return v; }
DEVI float rmax_16_32(float v){ v = fmaxf(v,__shfl_xor(v,16)); v = fmaxf(v,__shfl_xor(v,32)); return v; }
DEVI float rsum_1_8(float v){ v += __shfl_xor(v,1); v += __shfl_xor(v,2); v += __shfl_xor(v,4); v += __shfl_xor(v,8); return v; }
DEVI float rmax_1_8(float v){ v = fmaxf(v,__shfl_xor(v,1)); v = fmaxf(v,__shfl_xor(v,2)); v = fmaxf(v,__shfl_xor(v,4)); v = fmaxf(v,__shfl_xor(v,8)); return v; }
DEVI float rsum_all(float v){ return rsum_16_32(rsum_1_8(v)); }
DEVI float rmax_all(float v){ return rmax_16_32(rmax_1_8(v)); }
DEVI float sel4(float a0, float a1, float a2, float a3, int r){
  float v = a0; v = (r == 1) ? a1 : v; v = (r == 2) ? a2 : v; v = (r == 3) ? a3 : v; return v;
}
DEVI float sigm(float x){ return 1.f / (1.f + __expf(-x)); }

constexpr float GSTEP = 2.0f / 127.0f;
DEVI float gxf(int n){ return (float)(n & 127) * GSTEP - 1.0f; }
DEVI float gyf(int n){ return (float)((n >> 7) & 127) * GSTEP - 1.0f; }

#define NEGINF (-__builtin_inff())

// ---------------------------------------------------------------- k_setup
// blk 0..3: fg_pos from mask; blk 4: cbuf constants; blk 5: wfragG build
__global__ __launch_bounds__(1024) void k_setup(
    const float* __restrict__ mask,
    const float* __restrict__ gw, const float* __restrict__ gb,
    const float* __restrict__ g_fg, const float* __restrict__ bln_fg,
    const float* __restrict__ w_fg, const float* __restrict__ b_fg,
    const float* __restrict__ k_fg_w, const float* __restrict__ v_fg_w,
    const float* __restrict__ k_bg_w, const float* __restrict__ v_bg_w,
    const float* __restrict__ mlp_bg_w,
    float* __restrict__ fg_pos, float* __restrict__ cbuf,
    unsigned short* __restrict__ wfragG)
{
  int t = threadIdx.x;
  if (blockIdx.x < 4) {
    int k = blockIdx.x;
    const float4* mp = (const float4*)(mask + (size_t)k * Nn);
    float sm = 0, sx = 0, sy = 0;
    #pragma unroll
    for (int i = 0; i < 4; ++i) {
      int idx = t + i * 1024;
      float4 v = mp[idx];
      int n = idx * 4;
      float gy = gyf(n);
      float rowsum = v.x + v.y + v.z + v.w;
      sm += rowsum;
      sx += v.x * gxf(n) + v.y * gxf(n + 1) + v.z * gxf(n + 2) + v.w * gxf(n + 3);
      sy += rowsum * gy;
    }
    sm = rsum_all(sm); sx = rsum_all(sx); sy = rsum_all(sy);
    __shared__ float red[3][16];
    int wv = t >> 6, l = t & 63;
    if (l == 0) { red[0][wv] = sm; red[1][wv] = sx; red[2][wv] = sy; }
    __syncthreads();
    if (t == 0) {
      float S = 0, X = 0, Y = 0;
      #pragma unroll
      for (int i = 0; i < 16; ++i) { S += red[0][i]; X += red[1][i]; Y += red[2][i]; }
      float inv = 1.f / (S + 1e-5f);
      float px = X * inv, py = Y * inv;
      for (int b = 0; b < 4; ++b) { fg_pos[(b*4+k)*2+0] = px; fg_pos[(b*4+k)*2+1] = py; }
    }
  } else if (blockIdx.x == 4) {
    if (t < 64) {
      float gx_t = gw[t*4+0] - gw[t*4+2];
      float gy_t = gw[t*4+1] - gw[t*4+3];
      float aGx = 0, aGy = 0, agW = 0, aC0 = 0;
      for (int c = 0; c < 64; ++c) {
        float wv = w_fg[t*64 + c];
        float gc = g_fg[c];
        float gxc = gw[c*4+0] - gw[c*4+2];
        float gyc = gw[c*4+1] - gw[c*4+3];
        aGx += gxc * gc * wv;
        aGy += gyc * gc * wv;
        agW += gc * wv;
        aC0 += bln_fg[c] * wv;
      }
      cbuf[t] = aGx; cbuf[64+t] = aGy; cbuf[128+t] = agW; cbuf[192+t] = aC0 + b_fg[t];
      float mgx = rsum_all(gx_t) * (1.f/64.f);
      float mgy = rsum_all(gy_t) * (1.f/64.f);
      float egx2 = rsum_all(gx_t*gx_t) * (1.f/64.f);
      float egy2 = rsum_all(gy_t*gy_t) * (1.f/64.f);
      float egxy = rsum_all(gx_t*gy_t) * (1.f/64.f);
      if (t == 0) { cbuf[256]=mgx; cbuf[257]=mgy; cbuf[258]=egx2; cbuf[259]=egy2; cbuf[260]=egxy; }
    }
  } else {
    // wfragG: [mi][f][l] -> 8 bf16 each; mi order: kfg,vfg,kbg,vbg,mlp_bg,mlp_fg
    const float* wsrc[6] = { k_fg_w, v_fg_w, k_bg_w, v_bg_w, mlp_bg_w, w_fg };
    for (int e = t; e < 6 * 8 * 64; e += 1024) {
      int mi = e >> 9;
      int f = (e >> 6) & 7;
      int l = e & 63;
      const float* ws = wsrc[mi];
      int ct = f >> 1, kh = f & 1;
      int row = ct * 16 + (l & 15);
      int c0 = ((l >> 4) << 3) + kh * 32;
      unsigned short* dst = wfragG + (size_t)e * 8;
      #pragma unroll
      for (int j = 0; j < 8; ++j) dst[j] = f2bf(ws[row * 64 + c0 + j]);
    }
  }
}

// ---------------------------------------------------------------- k_prep (+ slot init tail)
__global__ __launch_bounds__(256) void k_prep(
    const float* __restrict__ feat,
    const float* __restrict__ norm_g, const float* __restrict__ norm_b,
    const float* __restrict__ gw, const float* __restrict__ gb,
    const float* __restrict__ mlp_bg_ln_g, const float* __restrict__ mlp_bg_ln_b,
    const float* __restrict__ mlp_bg_b, const float* __restrict__ mlp_fg_ln_g,
    const unsigned short* __restrict__ wfragG,
    unsigned short* __restrict__ A_k, unsigned short* __restrict__ A_vT,
    float* __restrict__ statsKV,
    unsigned short* __restrict__ kbg, unsigned short* __restrict__ vbg,
    const float* __restrict__ noise_fg, const float* __restrict__ noise_bg,
    const float* __restrict__ mu, const float* __restrict__ ls,
    const float* __restrict__ mub, const float* __restrict__ lsb,
    const float* __restrict__ q_ln_g, const float* __restrict__ q_ln_b, const float* __restrict__ q_w,
    const float* __restrict__ qbg_ln_g, const float* __restrict__ qbg_ln_b, const float* __restrict__ qbg_w,
    const float* __restrict__ cbuf,
    float* slot_fg, float* slot_bg, float* q_fg, float* q_bg, float* qscal)
{
  int tid = threadIdx.x, wave = tid >> 6, l = tid & 63;
  if ((int)blockIdx.x >= 512) {
    // ---- init tail: 20 blocks, wave 0 active
    __shared__ float lds[64];
    int ib = blockIdx.x - 512;
    float lnv = 0.f;
    if (tid < 64) {
      if (ib < 16) {
        float s = mu[tid] + expf(ls[tid]) * noise_fg[ib * 64 + tid];
        slot_fg[ib * 64 + tid] = s;
        float mean = rsum_all(s) * (1.f / 64.f);
        float d = s - mean;
        float var = rsum_all(d * d) * (1.f / 64.f);
        lnv = d * rsqrtf(var + 1e-5f) * q_ln_g[tid] + q_ln_b[tid];
      } else {
        int b = ib - 16;
        float s = mub[tid] + expf(lsb[tid]) * noise_bg[b * 64 + tid];
        slot_bg[b * 64 + tid] = s;
        float mean = rsum_all(s) * (1.f / 64.f);
        float d = s - mean;
        float var = rsum_all(d * d) * (1.f / 64.f);
        lnv = d * rsqrtf(var + 1e-5f) * qbg_ln_g[tid] + qbg_ln_b[tid];
      }
      lds[tid] = lnv;
    }
    __syncthreads();
    if (tid < 64) {
      if (ib < 16) {
        float acc = 0.f;
        #pragma unroll 8
        for (int c = 0; c < 64; ++c) acc += q_w[tid * 64 + c] * lds[c];
        q_fg[ib * 64 + tid] = acc;
        float qGx = rsum_all(acc * cbuf[tid]);
        float qGy = rsum_all(acc * cbuf[64 + tid]);
        float qgW = rsum_all(acc * cbuf[128 + tid]);
        float qC0 = rsum_all(acc * cbuf[192 + tid]);
        if (tid == 0) { qscal[ib*4+0]=qGx; qscal[ib*4+1]=qGy; qscal[ib*4+2]=qgW; qscal[ib*4+3]=qC0; }
      } else {
        int b = ib - 16;
        float acc = 0.f;
        #pragma unroll 8
        for (int c = 0; c < 64; ++c) acc += qbg_w[tid * 64 + c] * lds[c];
        q_bg[b * 64 + tid] = acc;
      }
    }
    return;
  }
  __shared__ __align__(16) unsigned short tbuf[4][16][88];
  __shared__ float s_gwx[64], s_gwy[64], s_gb[64], s_mlg[64], s_mlb[64], s_mbb[64], s_gf[64];
  if (tid < 64) {
    s_gwx[tid] = gw[tid*4+0] - gw[tid*4+2];
    s_gwy[tid] = gw[tid*4+1] - gw[tid*4+3];
    s_gb[tid]  = gb[tid];
    s_mlg[tid] = mlp_bg_ln_g[tid];
    s_mlb[tid] = mlp_bg_ln_b[tid];
    s_mbb[tid] = mlp_bg_b[tid];
    s_gf[tid]  = mlp_fg_ln_g[tid];
  }
  __syncthreads();

  int cb = (l >> 4) << 3;
  float ngr[16], nbr[16];
  #pragma unroll
  for (int j = 0; j < 16; ++j) {
    int col = (j < 8) ? (cb + j) : (32 + cb + j - 8);
    ngr[j] = norm_g[col]; nbr[j] = norm_b[col];
  }
  float gwxD[4], gwyD[4], gbD[4], mlgD[4], mlbD[4], mbbD[4], gfD[4];
  #pragma unroll
  for (int ct = 0; ct < 4; ++ct) {
    int col = ct * 16 + (l & 15);
    gwxD[ct] = s_gwx[col]; gwyD[ct] = s_gwy[col]; gbD[ct] = s_gb[col];
    mlgD[ct] = s_mlg[col]; mlbD[ct] = s_mlb[col]; mbbD[ct] = s_mbb[col];
    gfD[ct] = s_gf[col];
  }

  int wg = blockIdx.x * 4 + wave;
  for (int tt = 0; tt < 2; ++tt) {
    int tile = wg * 2 + tt;
    int rowg = tile * 16 + (l & 15);
    const float* fp = feat + (size_t)rowg * 64;
    float x[16];
    #pragma unroll
    for (int j = 0; j < 8; ++j) x[j] = fp[cb + j];
    #pragma unroll
    for (int j = 0; j < 8; ++j) x[8 + j] = fp[32 + cb + j];
    float sm = 0;
    #pragma unroll
    for (int j = 0; j < 16; ++j) sm += x[j];
    float mean = rsum_16_32(sm) * (1.f / 64.f);
    float vv = 0;
    #pragma unroll
    for (int j = 0; j < 16; ++j) { float d = x[j] - mean; vv += d * d; }
    float rstd = rsqrtf(rsum_16_32(vv) * (1.f / 64.f) + 1e-5f);
    bf16x8 a0, a1;
    #pragma unroll
    for (int j = 0; j < 8; ++j) a0[j] = (short)f2bf((x[j] - mean) * rstd * ngr[j] + nbr[j]);
    #pragma unroll
    for (int j = 0; j < 8; ++j) a1[j] = (short)f2bf((x[8 + j] - mean) * rstd * ngr[8 + j] + nbr[8 + j]);

    for (int mi = 0; mi < 4; ++mi) {
      bf16x8 wA[8];
      #pragma unroll
      for (int f = 0; f < 8; ++f) wA[f] = *(const bf16x8*)(wfragG + ((size_t)(mi * 8 + f) * 64 + l) * 8);
      f32x4 acc[4];
      #pragma unroll
      for (int ct = 0; ct < 4; ++ct) acc[ct] = (f32x4){0.f, 0.f, 0.f, 0.f};
      #pragma unroll
      for (int ct = 0; ct < 4; ++ct) {
        acc[ct] = __builtin_amdgcn_mfma_f32_16x16x32_bf16(a0, wA[ct * 2 + 0], acc[ct], 0, 0, 0);
        acc[ct] = __builtin_amdgcn_mfma_f32_16x16x32_bf16(a1, wA[ct * 2 + 1], acc[ct], 0, 0, 0);
      }
      if (mi < 2) {
        #pragma unroll
        for (int ct = 0; ct < 4; ++ct)
          #pragma unroll
          for (int r = 0; r < 4; ++r)
            acc[ct][r] += gbD[ct];
        float s1[4], s2[4], sx[4], sy[4];
        #pragma unroll
        for (int r = 0; r < 4; ++r) {
          float a0v = acc[0][r], a1v = acc[1][r], a2v = acc[2][r], a3v = acc[3][r];
          s1[r] = rsum_1_8(a0v + a1v + a2v + a3v);
          s2[r] = rsum_1_8(a0v*a0v + a1v*a1v + a2v*a2v + a3v*a3v);
          sx[r] = rsum_1_8(a0v*gwxD[0] + a1v*gwxD[1] + a2v*gwxD[2] + a3v*gwxD[3]);
          sy[r] = rsum_1_8(a0v*gwyD[0] + a1v*gwyD[1] + a2v*gwyD[2] + a3v*gwyD[3]);
        }
        int rsel = l & 15;
        if (rsel < 4) {
          float4 stv;
          stv.x = sel4(s1[0], s1[1], s1[2], s1[3], rsel) * (1.f/64.f);
          stv.y = sel4(s2[0], s2[1], s2[2], s2[3], rsel) * (1.f/64.f);
          stv.z = sel4(sx[0], sx[1], sx[2], sx[3], rsel) * (1.f/64.f);
          stv.w = sel4(sy[0], sy[1], sy[2], sy[3], rsel) * (1.f/64.f);
          int frow = tile * 16 + (l >> 4) * 4 + rsel;
          *(float4*)(statsKV + (size_t)frow * 8 + mi * 4) = stv;
        }
        #pragma unroll
        for (int ct = 0; ct < 4; ++ct)
          #pragma unroll
          for (int r = 0; r < 4; ++r)
            tbuf[wave][(l >> 4) * 4 + r][ct * 16 + (l & 15)] = f2bf(acc[ct][r] * gfD[ct]);
        bf16x8 b0 = *(const bf16x8*)&tbuf[wave][l & 15][cb];
        bf16x8 b1 = *(const bf16x8*)&tbuf[wave][l & 15][32 + cb];
        bf16x8 wB[8];
        #pragma unroll
        for (int f = 0; f < 8; ++f) wB[f] = *(const bf16x8*)(wfragG + ((size_t)(5 * 8 + f) * 64 + l) * 8);
        f32x4 acc2[4];
        #pragma unroll
        for (int ct = 0; ct < 4; ++ct) acc2[ct] = (f32x4){0.f, 0.f, 0.f, 0.f};
        #pragma unroll
        for (int ct = 0; ct < 4; ++ct) {
          acc2[ct] = __builtin_amdgcn_mfma_f32_16x16x32_bf16(b0, wB[ct * 2 + 0], acc2[ct], 0, 0, 0);
          acc2[ct] = __builtin_amdgcn_mfma_f32_16x16x32_bf16(b1, wB[ct * 2 + 1], acc2[ct], 0, 0, 0);
        }
        if (mi == 0) {
          #pragma unroll
          for (int ct = 0; ct < 4; ++ct)
            #pragma unroll
            for (int r = 0; r < 4; ++r)
              tbuf[wave][(l >> 4) * 4 + r][ct * 16 + (l & 15)] = f2bf(acc2[ct][r]);
          u16x8 o0 = *(const u16x8*)&tbuf[wave][l & 15][cb];
          u16x8 o1 = *(const u16x8*)&tbuf[wave][l & 15][32 + cb];
          *(u16x8*)(A_k + (size_t)rowg * 64 + cb) = o0;
          *(u16x8*)(A_k + (size_t)rowg * 64 + 32 + cb) = o1;
        } else {
          // tiled transposed layout: A_vT[((bb*NT + tloc)*64 + d)*16 + (n&15)]
          int bb = tile >> 10;
          int tloc = tile & (NT - 1);
          int offn = (l >> 4) << 2;
          #pragma unroll
          for (int ct = 0; ct < 4; ++ct) {
            u16x4 u4;
            u4[0] = f2bf(acc2[ct][0]); u4[1] = f2bf(acc2[ct][1]);
            u4[2] = f2bf(acc2[ct][2]); u4[3] = f2bf(acc2[ct][3]);
            int d = ct * 16 + (l & 15);
            *(u16x4*)(A_vT + (((size_t)bb * NT + tloc) * 64 + d) * 16 + offn) = u4;
          }
        }
      } else {
        #pragma unroll
        for (int ct = 0; ct < 4; ++ct)
          #pragma unroll
          for (int r = 0; r < 4; ++r) {
            int n = (tile * 16 + (l >> 4) * 4 + r) & (Nn - 1);
            acc[ct][r] += gwxD[ct] * gxf(n) + gwyD[ct] * gyf(n) + gbD[ct];
          }
        float mrow[4], rstd2[4];
        #pragma unroll
        for (int r = 0; r < 4; ++r) {
          float srow = acc[0][r] + acc[1][r] + acc[2][r] + acc[3][r];
          srow = rsum_1_8(srow);
          mrow[r] = srow * (1.f / 64.f);
          float vr = 0;
          #pragma unroll
          for (int ct = 0; ct < 4; ++ct) { float d = acc[ct][r] - mrow[r]; vr += d * d; }
          vr = rsum_1_8(vr);
          rstd2[r] = rsqrtf(vr * (1.f / 64.f) + 1e-5f);
        }
        #pragma unroll
        for (int ct = 0; ct < 4; ++ct)
          #pragma unroll
          for (int r = 0; r < 4; ++r)
            tbuf[wave][(l >> 4) * 4 + r][ct * 16 + (l & 15)] =
                f2bf((acc[ct][r] - mrow[r]) * rstd2[r] * mlgD[ct] + mlbD[ct]);
        bf16x8 b0 = *(const bf16x8*)&tbuf[wave][l & 15][cb];
        bf16x8 b1 = *(const bf16x8*)&tbuf[wave][l & 15][32 + cb];
        bf16x8 wB[8];
        #pragma unroll
        for (int f = 0; f < 8; ++f) wB[f] = *(const bf16x8*)(wfragG + ((size_t)(4 * 8 + f) * 64 + l) * 8);
        f32x4 acc2[4];
        #pragma unroll
        for (int ct = 0; ct < 4; ++ct) acc2[ct] = (f32x4){0.f, 0.f, 0.f, 0.f};
        #pragma unroll
        for (int ct = 0; ct < 4; ++ct) {
          acc2[ct] = __builtin_amdgcn_mfma_f32_16x16x32_bf16(b0, wB[ct * 2 + 0], acc2[ct], 0, 0, 0);
          acc2[ct] = __builtin_amdgcn_mfma_f32_16x16x32_bf16(b1, wB[ct * 2 + 1], acc2[ct], 0, 0, 0);
        }
        #pragma unroll
        for (int ct = 0; ct < 4; ++ct)
          #pragma unroll
          for (int r = 0; r < 4; ++r)
            tbuf[wave][(l >> 4) * 4 + r][ct * 16 + (l & 15)] = f2bf(acc2[ct][r] + mbbD[ct]);
        unsigned short* dst = (mi == 2) ? kbg : vbg;
        u16x8 o0 = *(const u16x8*)&tbuf[wave][l & 15][cb];
        u16x8 o1 = *(const u16x8*)&tbuf[wave][l & 15][32 + cb];
        *(u16x8*)(dst + (size_t)rowg * 64 + cb) = o0;
        *(u16x8*)(dst + (size_t)rowg * 64 + 32 + cb) = o1;
      }
    }
  }
}

// ---------------------------------------------------------------- k_iter (fg + bg partials only)
__global__ __launch_bounds__(256) void k_iter(
    const unsigned short* __restrict__ A_k, const unsigned short* __restrict__ A_vT,
    const float* __restrict__ statsKV,
    const unsigned short* __restrict__ kbg, const unsigned short* __restrict__ vbg,
    const float* __restrict__ q_fg, const float* __restrict__ q_bg,
    const float* __restrict__ fg_pos, const float* __restrict__ mask,
    const float* __restrict__ cbuf, const float* __restrict__ qscal,
    float* __restrict__ fgP, float* __restrict__ bgP)
{
  __shared__ float qa_pl[4][260];
  __shared__ __align__(16) unsigned short w_buf[4][272];
  __shared__ float redv[4][4][64];
  __shared__ float shred[4][130];
  int tid = threadIdx.x, wave = tid >> 6, l = tid & 63;
  if ((int)blockIdx.x < FG_BLK) {
    int b = blockIdx.x >> 6, ch = blockIdx.x & 63;
    int n0 = ch * CH;
    int slot = l & 15;
    bf16x8 qf0, qf1;
    {
      int bkq = b * 4 + (slot & 3);
      #pragma unroll
      for (int j = 0; j < 8; ++j) {
        float v0 = q_fg[bkq * 64 + (l >> 4) * 8 + j];
        float v1 = q_fg[bkq * 64 + 32 + (l >> 4) * 8 + j];
        qf0[j] = (short)f2bf(slot < 4 ? v0 : 0.f);
        qf1[j] = (short)f2bf(slot < 4 ? v1 : 0.f);
      }
    }
    // phase 0: qA = q @ A_k^T (4 tiles per wave, unrolled for ILP)
    #pragma unroll
    for (int tt2 = 0; tt2 < 4; ++tt2) {
      int t = wave * 4 + tt2;
      const unsigned short* ap = A_k + ((size_t)b * Nn + n0 + t * 16 + (l & 15)) * 64 + ((l >> 4) << 3);
      bf16x8 b0 = *(const bf16x8*)ap;
      bf16x8 b1 = *(const bf16x8*)(ap + 32);
      f32x4 acc = (f32x4){0.f, 0.f, 0.f, 0.f};
      acc = __builtin_amdgcn_mfma_f32_16x16x32_bf16(qf0, b0, acc, 0, 0, 0);
      acc = __builtin_amdgcn_mfma_f32_16x16x32_bf16(qf1, b1, acc, 0, 0, 0);
      if (l < 16) {
        #pragma unroll
        for (int r = 0; r < 4; ++r) qa_pl[r][t * 16 + l] = acc[r];
      }
    }
    __syncthreads();
    // phase A: wave w owns slot w
    int w = wave;
    float pxw = fg_pos[(b * 4 + w) * 2 + 0], pyw = fg_pos[(b * 4 + w) * 2 + 1];
    float qGx = qscal[(b*4+w)*4+0], qGy = qscal[(b*4+w)*4+1];
    float qgW = qscal[(b*4+w)*4+2], qC0 = qscal[(b*4+w)*4+3];
    float mgx = cbuf[256], mgy = cbuf[257], egx2 = cbuf[258], egy2 = cbuf[259], egxy = cbuf[260];
    float lgc[4], rsv[4], muvc[4];
    float mx = NEGINF;
    #pragma unroll
    for (int i = 0; i < 4; ++i) {
      int n = n0 + i * 64 + l;
      const float* st = statsKV + ((size_t)b * Nn + n) * 8;
      float4 sk = *(const float4*)st;
      float4 sv = *(const float4*)(st + 4);
      float gx = gxf(n), gy = gyf(n);
      float relx = gx - pxw, rely = gy - pyw;
      float mu = sk.x + relx * mgx + rely * mgy;
      float ex2 = sk.y + 2.f*(relx*sk.z + rely*sk.w) + relx*relx*egx2 + rely*rely*egy2 + 2.f*relx*rely*egxy;
      float rstd = rsqrtf(fmaxf(ex2 - mu * mu, 0.f) + 1e-5f);
      float qa = qa_pl[w][i * 64 + l];
      float lg = 0.125f * (rstd * (qa + relx * qGx + rely * qGy - mu * qgW) + qC0);
      float mk = mask[w * Nn + n];
      lg = (mk == 0.f) ? -1e9f : lg;
      lgc[i] = lg; mx = fmaxf(mx, lg);
      float muv = sv.x + relx * mgx + rely * mgy;
      float ex2v = sv.y + 2.f*(relx*sv.z + rely*sv.w) + relx*relx*egx2 + rely*rely*egy2 + 2.f*relx*rely*egxy;
      rsv[i] = rsqrtf(fmaxf(ex2v - muv * muv, 0.f) + 1e-5f);
      muvc[i] = muv;
    }
    float mb = rmax_all(mx);
    float s_a = 0, px_a = 0, py_a = 0, swx = 0, swy = 0, swm = 0;
    #pragma unroll
    for (int i = 0; i < 4; ++i) {
      int n = n0 + i * 64 + l;
      float e = __expf(lgc[i] - mb);
      float gx = gxf(n), gy = gyf(n);
      s_a += e; px_a += e * gx; py_a += e * gy;
      float wgt = e * rsv[i];
      swx += wgt * (gx - pxw); swy += wgt * (gy - pyw); swm += wgt * muvc[i];
      w_buf[w][i * 64 + l] = f2bf(wgt);
    }
    s_a = rsum_all(s_a); px_a = rsum_all(px_a); py_a = rsum_all(py_a);
    swx = rsum_all(swx); swy = rsum_all(swy); swm = rsum_all(swm);
    if (l == 0) {
      float* P = fgP + ((size_t)(b * NCH + ch) * 4 + w) * FG_PS;
      P[0] = mb; P[1] = s_a; P[2] = px_a; P[3] = py_a; P[4] = swx; P[5] = swy; P[6] = swm;
    }
    __syncthreads();
    // phase B: upd = w(4xCH) @ A_v(CHx64)  -- A_vT tiled layout
    f32x4 acc[4];
    #pragma unroll
    for (int ct = 0; ct < 4; ++ct) acc[ct] = (f32x4){0.f, 0.f, 0.f, 0.f};
    bf16x8 zz;
    #pragma unroll
    for (int j = 0; j < 8; ++j) zz[j] = 0;
    #pragma unroll
    for (int st2 = 0; st2 < 2; ++st2) {
      int noff = wave * 64 + st2 * 32;
      bf16x8 wf = *(const bf16x8*)&w_buf[l & 3][noff + ((l >> 4) << 3)];
      if ((l & 15) >= 4) wf = zz;
      int nst = n0 + noff + ((l >> 4) << 3);
      #pragma unroll
      for (int ct = 0; ct < 4; ++ct) {
        const unsigned short* ap = A_vT + (((size_t)b * NT + (nst >> 4)) * 64 + ct * 16 + (l & 15)) * 16 + (nst & 15);
        bf16x8 bv = *(const bf16x8*)ap;
        acc[ct] = __builtin_amdgcn_mfma_f32_16x16x32_bf16(wf, bv, acc[ct], 0, 0, 0);
      }
    }
    if (l < 16) {
      #pragma unroll
      for (int ct = 0; ct < 4; ++ct)
        #pragma unroll
        for (int r = 0; r < 4; ++r)
          redv[wave][r][ct * 16 + l] = acc[ct][r];
    }
    __syncthreads();
    if (wave == 0) {
      #pragma unroll
      for (int s2 = 0; s2 < 4; ++s2) {
        float v = redv[0][s2][l] + redv[1][s2][l] + redv[2][s2][l] + redv[3][s2][l];
        fgP[((size_t)(b * NCH + ch) * 4 + s2) * FG_PS + 8 + l] = v;
      }
    }
  } else {
    int idx = blockIdx.x - FG_BLK;
    int b = idx >> 6, nb = idx & 63;
    int cb16 = (l >> 4) << 4;
    float qr[16];
    #pragma unroll
    for (int i = 0; i < 16; ++i) qr[i] = q_bg[b * 64 + cb16 + i];
    float m = NEGINF, s = 0.f, upd[16], sv[16];
    #pragma unroll
    for (int i = 0; i < 16; ++i) { upd[i] = 0; sv[i] = 0; }
    #pragma unroll
    for (int pass = 0; pass < 4; ++pass) {
      int nrow = nb * 256 + pass * 64 + wave * 16 + (l & 15);
      const unsigned short* kp = kbg + ((size_t)b * Nn + nrow) * 64 + cb16;
      const unsigned short* vp = vbg + ((size_t)b * Nn + nrow) * 64 + cb16;
      u16x8 k0 = *(const u16x8*)kp, k1 = *(const u16x8*)(kp + 8);
      u16x8 v0 = *(const u16x8*)vp, v1 = *(const u16x8*)(vp + 8);
      float p = 0;
      #pragma unroll
      for (int i = 0; i < 8; ++i) { p += qr[i] * bf2f(k0[i]); p += qr[8 + i] * bf2f(k1[i]); }
      p = rsum_16_32(p);
      float lg = 0.125f * p;
      float tm = rmax_1_8(lg);
      float mnew = fmaxf(m, tm);
      float alpha = __expf(m - mnew); m = mnew;
      s *= alpha;
      #pragma unroll
      for (int i = 0; i < 16; ++i) upd[i] *= alpha;
      float e = __expf(lg - mnew);
      s += e;
      #pragma unroll
      for (int i = 0; i < 8; ++i) {
        float fv0 = bf2f(v0[i]), fv1 = bf2f(v1[i]);
        upd[i] += e * fv0; upd[8 + i] += e * fv1;
        sv[i] += fv0; sv[8 + i] += fv1;
      }
    }
    s = rsum_1_8(s);
    #pragma unroll
    for (int i = 0; i < 16; ++i) { upd[i] = rsum_1_8(upd[i]); sv[i] = rsum_1_8(sv[i]); }
    if (l == 0) { shred[wave][0] = m; shred[wave][1] = s; }
    if ((l & 15) == 0) {
      int g = l >> 4;
      #pragma unroll
      for (int i = 0; i < 16; ++i) { shred[wave][2 + g * 16 + i] = upd[i]; shred[wave][66 + g * 16 + i] = sv[i]; }
    }
    __syncthreads();
    if (wave == 0) {
      float m0 = shred[0][0], m1 = shred[1][0], m2 = shred[2][0], m3 = shred[3][0];
      float mg = fmaxf(fmaxf(m0, m1), fmaxf(m2, m3));
      float w0 = __expf(m0 - mg), w1 = __expf(m1 - mg), w2 = __expf(m2 - mg), w3 = __expf(m3 - mg);
      float* P = bgP + (size_t)idx * BG_PS;
      P[2 + l]  = w0 * shred[0][2 + l] + w1 * shred[1][2 + l] + w2 * shred[2][2 + l] + w3 * shred[3][2 + l];
      P[66 + l] = shred[0][66 + l] + shred[1][66 + l] + shred[2][66 + l] + shred[3][66 + l];
      if (l == 0) {
        P[0] = mg;
        P[1] = w0 * shred[0][1] + w1 * shred[1][1] + w2 * shred[2][1] + w3 * shred[3][1];
      }
    }
  }
}

// ---------------------------------------------------------------- k_comb
__global__ __launch_bounds__(256) void k_comb(
    const float* __restrict__ fgP, const float* __restrict__ bgP,
    float* slot_fg, float* slot_bg,
    float* q_fg, float* q_bg, float* fg_pos, float* qscal,
    const float* __restrict__ cbuf,
    const float* __restrict__ gru_fg_wih, const float* __restrict__ gru_fg_whh,
    const float* __restrict__ gru_fg_bih, const float* __restrict__ gru_fg_bhh,
    const float* __restrict__ gru_bg_wih, const float* __restrict__ gru_bg_whh,
    const float* __restrict__ gru_bg_bih, const float* __restrict__ gru_bg_bhh,
    const float* __restrict__ res_fg_ln_g, const float* __restrict__ res_fg_ln_b,
    const float* __restrict__ res_fg_w, const float* __restrict__ res_fg_b,
    const float* __restrict__ res_bg_ln_g, const float* __restrict__ res_bg_ln_b,
    const float* __restrict__ res_bg_w, const float* __restrict__ res_bg_b,
    const float* __restrict__ q_ln_g, const float* __restrict__ q_ln_b, const float* __restrict__ q_w,
    const float* __restrict__ qbg_ln_g, const float* __restrict__ qbg_ln_b, const float* __restrict__ qbg_w,
    float* __restrict__ dout)
{
  __shared__ float wl[64];
  __shared__ float ubuf[4][64];
  __shared__ float part[4][64];
  __shared__ float xs[64], hs[64];
  __shared__ float gd[384];
  __shared__ float scal[6];
  int tid = threadIdx.x, wv = tid >> 6, l = tid & 63;
  int blk = blockIdx.x;
  if (blk < 16) {
    int bk = blk, b = bk >> 2, k = bk & 3;
    if (wv == 0) {
      const float* pp = fgP + ((size_t)(b * NCH + l) * 4 + k) * FG_PS;
      float mp = pp[0];
      float sp = pp[1];
      float pxp = pp[2];
      float pyp = pp[3];
      float sxp = pp[4];
      float syp = pp[5];
      float smp = pp[6];
      float mg = rmax_all(mp);
      float w = __expf(mp - mg);
      wl[l] = w;
      float S = rsum_all(w * sp);
      float px = rsum_all(w * pxp);
      float py = rsum_all(w * pyp);
      float sxg = rsum_all(w * sxp);
      float syg = rsum_all(w * syp);
      float smg = rsum_all(w * smp);
      if (l == 0) { scal[0]=S; scal[1]=px/S; scal[2]=py/S; scal[3]=sxg; scal[4]=syg; scal[5]=smg; }
    }
    __syncthreads();
    float S = scal[0];
    float acc = 0;
    #pragma unroll
    for (int i = 0; i < 16; ++i) {
      int c = wv * 16 + i;
      acc += wl[c] * fgP[((size_t)(b * NCH + c) * 4 + k) * FG_PS + 8 + l];
    }
    ubuf[wv][l] = acc;
    __syncthreads();
    if (wv == 0) {
      float UV = ubuf[0][l] + ubuf[1][l] + ubuf[2][l] + ubuf[3][l];
      float upd = (UV + scal[3] * cbuf[l] + scal[4] * cbuf[64 + l] - scal[5] * cbuf[128 + l]) / S + cbuf[192 + l];
      xs[l] = upd;
      hs[l] = slot_fg[bk * 64 + l];
    }
    __syncthreads();
    {
      int r = tid;
      float a;
      if (r < 192) {
        const float* w = gru_fg_wih + r * 64; a = gru_fg_bih[r];
        #pragma unroll 8
        for (int c = 0; c < 64; ++c) a += w[c] * xs[c];
      } else {
        const float* w = gru_fg_whh + (r - 192) * 64; a = gru_fg_bhh[r - 192];
        #pragma unroll 8
        for (int c = 0; c < 64; ++c) a += w[c] * hs[c];
      }
      gd[r] = a;
      if (tid < 128) {
        int r2 = tid + 256;
        const float* w = gru_fg_whh + (r2 - 192) * 64; float a2 = gru_fg_bhh[r2 - 192];
        #pragma unroll 8
        for (int c = 0; c < 64; ++c) a2 += w[c] * hs[c];
        gd[r2] = a2;
      }
    }
    __syncthreads();
    if (wv == 0) {
      float h = hs[l];
      float r = sigm(gd[l] + gd[192 + l]);
      float z = sigm(gd[64 + l] + gd[256 + l]);
      float nng = tanhf(gd[128 + l] + r * gd[320 + l]);
      float hnew = (1.f - z) * nng + z * h;
      float mean = rsum_all(hnew) * (1.f / 64.f);
      float d = hnew - mean;
      float var = rsum_all(d * d) * (1.f / 64.f);
      xs[l] = d * rsqrtf(var + 1e-5f) * res_fg_ln_g[l] + res_fg_ln_b[l];
    }
    __syncthreads();
    {
      int c0 = wv * 16;
      const float* w = res_fg_w + l * 64 + c0;
      float a = 0;
      #pragma unroll
      for (int c = 0; c < 16; ++c) a += w[c] * xs[c0 + c];
      part[wv][l] = a;
    }
    __syncthreads();
    if (wv == 0) {
      float h = hs[l];
      float snew = part[0][l] + part[1][l] + part[2][l] + part[3][l] + res_fg_b[l] + h;
      slot_fg[bk * 64 + l] = snew;
      dout[(b * 5 + 1 + k) * 64 + l] = snew;
      float mq = rsum_all(snew) * (1.f / 64.f);
      float dq = snew - mq;
      float vq = rsum_all(dq * dq) * (1.f / 64.f);
      xs[l] = dq * rsqrtf(vq + 1e-5f) * q_ln_g[l] + q_ln_b[l];
    }
    __syncthreads();
    {
      int c0 = wv * 16;
      const float* w = q_w + l * 64 + c0;
      float a = 0;
      #pragma unroll
      for (int c = 0; c < 16; ++c) a += w[c] * xs[c0 + c];
      part[wv][l] = a;
    }
    __syncthreads();
    if (wv == 0) {
      float qacc = part[0][l] + part[1][l] + part[2][l] + part[3][l];
      q_fg[bk * 64 + l] = qacc;
      float qGx = rsum_all(qacc * cbuf[l]);
      float qGy = rsum_all(qacc * cbuf[64 + l]);
      float qgW = rsum_all(qacc * cbuf[128 + l]);
      float qC0 = rsum_all(qacc * cbuf[192 + l]);
      if (l == 0) {
        qscal[bk*4+0]=qGx; qscal[bk*4+1]=qGy; qscal[bk*4+2]=qgW; qscal[bk*4+3]=qC0;
        float px = scal[1], py = scal[2];
        fg_pos[bk * 2 + 0] = px; fg_pos[bk * 2 + 1] = py;
        dout[1280 + bk * 2 + 0] = px; dout[1280 + bk * 2 + 1] = py;
      }
    }
  } else {
    int b = blk - 16;
    const float* P = bgP + (size_t)b * NBG * BG_PS;
    if (wv == 0) {
      float mp = P[l * BG_PS + 0];
      float sp = P[l * BG_PS + 1];
      float mg = rmax_all(mp);
      float w = __expf(mp - mg);
      wl[l] = w;
      float S = rsum_all(w * sp);
      if (l == 0) scal[0] = S;
    }
    __syncthreads();
    float S = scal[0];
    float acc = 0, sva = 0;
    #pragma unroll
    for (int i = 0; i < 16; ++i) {
      int p = wv * 16 + i;
      acc += wl[p] * P[(size_t)p * BG_PS + 2 + l];
      sva += P[(size_t)p * BG_PS + 66 + l];
    }
    ubuf[wv][l] = acc; part[wv][l] = sva;
    __syncthreads();
    if (wv == 0) {
      float upd = (ubuf[0][l] + ubuf[1][l] + ubuf[2][l] + ubuf[3][l]) / S
                + 1e-8f * (part[0][l] + part[1][l] + part[2][l] + part[3][l]);
      xs[l] = upd;
      hs[l] = slot_bg[b * 64 + l];
    }
    __syncthreads();
    {
      int r = tid;
      float a;
      if (r < 192) {
        const float* w = gru_bg_wih + r * 64; a = gru_bg_bih[r];
        #pragma unroll 8
        for (int c = 0; c < 64; ++c) a += w[c] * xs[c];
      } else {
        const float* w = gru_bg_whh + (r - 192) * 64; a = gru_bg_bhh[r - 192];
        #pragma unroll 8
        for (int c = 0; c < 64; ++c) a += w[c] * hs[c];
      }
      gd[r] = a;
      if (tid < 128) {
        int r2 = tid + 256;
        const float* w = gru_bg_whh + (r2 - 192) * 64; float a2 = gru_bg_bhh[r2 - 192];
        #pragma unroll 8
        for (int c = 0; c < 64; ++c) a2 += w[c] * hs[c];
        gd[r2] = a2;
      }
    }
    __syncthreads();
    if (wv == 0) {
      float h = hs[l];
      float r = sigm(gd[l] + gd[192 + l]);
      float z = sigm(gd[64 + l] + gd[256 + l]);
      float nng = tanhf(gd[128 + l] + r * gd[320 + l]);
      float hnew = (1.f - z) * nng + z * h;
      float mean = rsum_all(hnew) * (1.f / 64.f);
      float d = hnew - mean;
      float var = rsum_all(d * d) * (1.f / 64.f);
      xs[l] = d * rsqrtf(var + 1e-5f) * res_bg_ln_g[l] + res_bg_ln_b[l];
    }
    __syncthreads();
    {
      int c0 = wv * 16;
      const float* w = res_bg_w + l * 64 + c0;
      float a = 0;
      #pragma unroll
      for (int c = 0; c < 16; ++c) a += w[c] * xs[c0 + c];
      part[wv][l] = a;
    }
    __syncthreads();
    if (wv == 0) {
      float h = hs[l];
      float snew = part[0][l] + part[1][l] + part[2][l] + part[3][l] + res_bg_b[l] + h;
      slot_bg[b * 64 + l] = snew;
      dout[(b * 5 + 0) * 64 + l] = snew;
      float mq = rsum_all(snew) * (1.f / 64.f);
      float dq = snew - mq;
      float vq = rsum_all(dq * dq) * (1.f / 64.f);
      xs[l] = dq * rsqrtf(vq + 1e-5f) * qbg_ln_g[l] + qbg_ln_b[l];
    }
    __syncthreads();
    {
      int c0 = wv * 16;
      const float* w = qbg_w + l * 64 + c0;
      float a = 0;
      #pragma unroll
      for (int c = 0; c < 16; ++c) a += w[c] * xs[c0 + c];
      part[wv][l] = a;
    }
    __syncthreads();
    if (wv == 0) {
      q_bg[b * 64 + l] = part[0][l] + part[1][l] + part[2][l] + part[3][l];
    }
  }
}

// ---------------------------------------------------------------- launch
extern "C" void kernel_launch(void* const* d_in, const int* in_sizes, int n_in,
                              void* d_out, int out_size, void* d_ws, size_t ws_size,
                              hipStream_t stream)
{
  (void)in_sizes; (void)n_in; (void)out_size; (void)ws_size;
  const float* feat        = (const float*)d_in[0];
  const float* mask        = (const float*)d_in[1];
  const float* noise_fg    = (const float*)d_in[2];
  const float* noise_bg    = (const float*)d_in[3];
  const float* slots_mu    = (const float*)d_in[4];
  const float* slots_ls    = (const float*)d_in[5];
  const float* slots_mu_bg = (const float*)d_in[6];
  const float* slots_ls_bg = (const float*)d_in[7];
  const float* norm_feat_g = (const float*)d_in[8];
  const float* norm_feat_b = (const float*)d_in[9];
  const float* grid_embed_w= (const float*)d_in[10];
  const float* grid_embed_b= (const float*)d_in[11];
  const float* k_fg_w      = (const float*)d_in[12];
  const float* v_fg_w      = (const float*)d_in[13];
  const float* k_bg_w      = (const float*)d_in[14];
  const float* v_bg_w      = (const float*)d_in[15];
  const float* mlp_fg_ln_g = (const float*)d_in[16];
  const float* mlp_fg_ln_b = (const float*)d_in[17];
  const float* mlp_fg_w    = (const float*)d_in[18];
  const float* mlp_fg_b    = (const float*)d_in[19];
  const float* mlp_bg_ln_g = (const float*)d_in[20];
  const float* mlp_bg_ln_b = (const float*)d_in[21];
  const float* mlp_bg_w    = (const float*)d_in[22];
  const float* mlp_bg_b    = (const float*)d_in[23];
  const float* q_ln_g      = (const float*)d_in[24];
  const float* q_ln_b      = (const float*)d_in[25];
  const float* q_w         = (const float*)d_in[26];
  const float* qbg_ln_g    = (const float*)d_in[27];
  const float* qbg_ln_b    = (const float*)d_in[28];
  const float* qbg_w       = (const float*)d_in[29];
  const float* gru_fg_wih  = (const float*)d_in[30];
  const float* gru_fg_whh  = (const float*)d_in[31];
  const float* gru_fg_bih  = (const float*)d_in[32];
  const float* gru_fg_bhh  = (const float*)d_in[33];
  const float* gru_bg_wih  = (const float*)d_in[34];
  const float* gru_bg_whh  = (const float*)d_in[35];
  const float* gru_bg_bih  = (const float*)d_in[36];
  const float* gru_bg_bhh  = (const float*)d_in[37];
  const float* res_fg_ln_g = (const float*)d_in[38];
  const float* res_fg_ln_b = (const float*)d_in[39];
  const float* res_fg_w    = (const float*)d_in[40];
  const float* res_fg_b    = (const float*)d_in[41];
  const float* res_bg_ln_g = (const float*)d_in[42];
  const float* res_bg_ln_b = (const float*)d_in[43];
  const float* res_bg_w    = (const float*)d_in[44];
  const float* res_bg_b    = (const float*)d_in[45];
  float* dout = (float*)d_out;

  char* wsp = (char*)d_ws;
  size_t off = 0;
  auto alloc = [&](size_t bytes) -> void* {
    void* p = wsp + off;
    off += (bytes + 255) & ~(size_t)255;
    return p;
  };
  unsigned short* A_k  = (unsigned short*)alloc((size_t)Bb * Nn * 64 * 2);
  unsigned short* A_vT = (unsigned short*)alloc((size_t)Bb * Nn * 64 * 2);
  float* statsKV       = (float*)alloc((size_t)Bb * Nn * 8 * 4);
  unsigned short* kbg  = (unsigned short*)alloc((size_t)Bb * Nn * 64 * 2);
  unsigned short* vbg  = (unsigned short*)alloc((size_t)Bb * Nn * 64 * 2);
  unsigned short* wfragG = (unsigned short*)alloc(6 * 8 * 64 * 8 * 2);
  float* slot_fg = (float*)alloc(16 * 64 * 4);
  float* slot_bg = (float*)alloc(4 * 64 * 4);
  float* q_fg    = (float*)alloc(16 * 64 * 4);
  float* q_bg    = (float*)alloc(4 * 64 * 4);
  float* fg_pos  = (float*)alloc(16 * 2 * 4);
  float* qscal   = (float*)alloc(16 * 4 * 4);
  float* cbuf    = (float*)alloc(264 * 4);
  float* fgP     = (float*)alloc((size_t)Bb * NCH * 4 * FG_PS * 4);
  float* bgP     = (float*)alloc((size_t)BG_BLK * BG_PS * 4);

  k_setup<<<6, 1024, 0, stream>>>(mask, grid_embed_w, grid_embed_b, mlp_fg_ln_g, mlp_fg_ln_b,
                                  mlp_fg_w, mlp_fg_b,
                                  k_fg_w, v_fg_w, k_bg_w, v_bg_w, mlp_bg_w,
                                  fg_pos, cbuf, wfragG);
  k_prep<<<532, 256, 0, stream>>>(feat, norm_feat_g, norm_feat_b, grid_embed_w, grid_embed_b,
                                  mlp_bg_ln_g, mlp_bg_ln_b, mlp_bg_b, mlp_fg_ln_g,
                                  wfragG,
                                  A_k, A_vT, statsKV, kbg, vbg,
                                  noise_fg, noise_bg, slots_mu, slots_ls, slots_mu_bg, slots_ls_bg,
                                  q_ln_g, q_ln_b, q_w, qbg_ln_g, qbg_ln_b, qbg_w, cbuf,
                                  slot_fg, slot_bg, q_fg, q_bg, qscal);
  for (int it = 0; it < 4; ++it) {
    k_iter<<<FG_BLK + BG_BLK, 256, 0, stream>>>(A_k, A_vT, statsKV, kbg, vbg,
                                                q_fg, q_bg, fg_pos, mask, cbuf, qscal,
                                                fgP, bgP);
    k_comb<<<20, 256, 0, stream>>>(fgP, bgP, slot_fg, slot_bg, q_fg, q_bg, fg_pos, qscal, cbuf,
                                   gru_fg_wih, gru_fg_whh, gru_fg_bih, gru_fg_bhh,
                                   gru_bg_wih, gru_bg_whh, gru_bg_bih, gru_bg_bhh,
                                   res_fg_ln_g, res_fg_ln_b, res_fg_w, res_fg_b,
                                   res_bg_ln_g, res_bg_ln_b, res_bg_w, res_bg_b,
                                   q_ln_g, q_ln_b, q_w, qbg_ln_g, qbg_ln_b, qbg_w,
                                   dout);
  }
}